// Round 12
// baseline (334.928 us; speedup 1.0000x reference)
//
#include <hip/hip_runtime.h>
#include <cstdint>

// ---------------------------------------------------------------------------
// TransformerBlock: B=4, T=2048, D=1024, H=16, HD=64
// Pipeline: preprocess(cvt X + all W transposes, 1 launch) -> GEMM4(QKV)
//           -> transpose(V) -> flash-attn -> LN1(f16 in) -> GEMM4(FFN1,relu)
//           -> GEMM4(FFN2,+resid,f16) -> LN2
// All GEMMs on the 3-barrier gemm4 structure (BM=256,BN=128,BK=64, 8 waves
// 4Mx2N, two 16-MFMA clusters/K-tile, counted vmcnt(6)).
// Attention: log2-domain scores, swapped QK^T, no max tracking, raw v_exp_f32.
// ---------------------------------------------------------------------------

typedef _Float16 f16x8 __attribute__((ext_vector_type(8)));
typedef _Float16 f16x4 __attribute__((ext_vector_type(4)));
typedef float    f32x4 __attribute__((ext_vector_type(4)));

#define DEVI __device__ __forceinline__

typedef __attribute__((address_space(1))) uint32_t gas1_u32;
typedef __attribute__((address_space(3))) uint32_t las3_u32;

// async global->LDS, 16B per lane; LDS dest must be linear (base + lane*16)
DEVI void gl2lds16(const void* g, void* l) {
  __builtin_amdgcn_global_load_lds((gas1_u32*)(uintptr_t)g,
                                   (las3_u32*)(uintptr_t)l, 16, 0, 0);
}

#define FENCE_BAR                                                            \
  __builtin_amdgcn_sched_barrier(0xF);                                       \
  __builtin_amdgcn_s_barrier();                                              \
  __builtin_amdgcn_sched_barrier(0xF);

// ---------------------------------------------------------------------------
// Fused preprocessing (one launch):
//  blocks [0,4096):      X f32 -> Xh f16 (8 elems/thread)
//  blocks [4096,4864):   Wq/Wk/Wv [16 slices each of [1024][64]] -> Wqkv B^T
//  blocks [4864,5888):   W1 [1024][4096] -> W1t [4096][1024]
//  blocks [5888,6912):   W2 [4096][1024] -> W2t [1024][4096]
__global__ __launch_bounds__(256) void preprocess(
    const float* __restrict__ X, _Float16* __restrict__ Xh,
    const float* __restrict__ Wq, const float* __restrict__ Wk,
    const float* __restrict__ Wv, _Float16* __restrict__ Wqkv,
    const float* __restrict__ W1, _Float16* __restrict__ W1t,
    const float* __restrict__ W2, _Float16* __restrict__ W2t) {
  const int idx = blockIdx.x;
  const int tid = threadIdx.x;
  if (idx < 4096) {  // ---- cvt X ----
    const int i = (idx * 256 + tid) * 8;
    float4 a = *(const float4*)&X[i];
    float4 b = *(const float4*)&X[i + 4];
    f16x8 o;
    o[0] = (_Float16)a.x; o[1] = (_Float16)a.y; o[2] = (_Float16)a.z; o[3] = (_Float16)a.w;
    o[4] = (_Float16)b.x; o[5] = (_Float16)b.y; o[6] = (_Float16)b.z; o[7] = (_Float16)b.w;
    *(f16x8*)&Xh[i] = o;
    return;
  }
  __shared__ _Float16 T[64 * 72];
  const float* src;
  _Float16* dst;
  int k0, rowbase, stride, dstK;
  float scale = 1.0f;
  if (idx < 4864) {            // ---- Wq/Wk/Wv -> Wqkv ----
    const int j = idx - 4096;  // 0..767
    const int z = j >> 4;      // 0..47
    const int which = z >> 4;  // 0..2
    const int slice = z & 15;
    src = ((which == 0) ? Wq : (which == 1) ? Wk : Wv) + (size_t)slice * 65536;
    scale = (which == 0) ? 0.18033688011112042f : 1.0f;  // log2e/8
    k0 = (j & 15) * 64;
    rowbase = which * 1024 + slice * 64;
    stride = 64; dstK = 1024; dst = Wqkv;
  } else if (idx < 5888) {     // ---- W1 -> W1t ----
    const int j = idx - 4864;  // 0..1023
    src = W1 + (j >> 4) * 64;
    k0 = (j & 15) * 64;
    rowbase = (j >> 4) * 64;
    stride = 4096; dstK = 1024; dst = W1t;
  } else {                     // ---- W2 -> W2t ----
    const int j = idx - 5888;  // 0..1023
    src = W2 + (j >> 6) * 64;
    k0 = (j & 63) * 64;
    rowbase = (j >> 6) * 64;
    stride = 1024; dstK = 4096; dst = W2t;
  }
#pragma unroll
  for (int p = 0; p < 4; ++p) {
    int c = p * 256 + tid;           // 0..1023
    int kl = c >> 4;                 // 0..63
    int nl = (c & 15) * 4;           // 0..60
    float4 v = *(const float4*)&src[(size_t)(k0 + kl) * stride + nl];
    T[(nl + 0) * 72 + kl] = (_Float16)(v.x * scale);
    T[(nl + 1) * 72 + kl] = (_Float16)(v.y * scale);
    T[(nl + 2) * 72 + kl] = (_Float16)(v.z * scale);
    T[(nl + 3) * 72 + kl] = (_Float16)(v.w * scale);
  }
  __syncthreads();
#pragma unroll
  for (int p = 0; p < 2; ++p) {
    int c = p * 256 + tid;           // 0..511
    int nl = c >> 3;                 // 0..63
    int kc = (c & 7) * 8;            // 0..56
    f16x8 vv = *(const f16x8*)&T[nl * 72 + kc];
    *(f16x8*)&dst[(size_t)(rowbase + nl) * dstK + k0 + kc] = vv;
  }
}

// ---------------------------------------------------------------------------
// V [bh][t][e=64] f16  ->  Vt [bh][e=64][t=2048] f16. grid (T/64, BH)
__global__ __launch_bounds__(256) void transpose_v(
    const _Float16* __restrict__ Vh, _Float16* __restrict__ Vt) {
  __shared__ _Float16 T[64 * 72];
  const int t0 = blockIdx.x * 64;
  const size_t hb = (size_t)blockIdx.y * (2048 * 64);
  const int tid = threadIdx.x;
#pragma unroll
  for (int it = 0; it < 2; ++it) {
    const int c = it * 256 + tid;   // 0..511
    const int tl = c >> 3;
    const int ec = (c & 7) * 8;
    *(f16x8*)&T[tl * 72 + ec] =
        *(const f16x8*)&Vh[hb + (size_t)(t0 + tl) * 64 + ec];
  }
  __syncthreads();
#pragma unroll
  for (int it = 0; it < 2; ++it) {
    const int c = it * 256 + tid;
    const int el = c >> 3;
    const int tc = (c & 7) * 8;
    f16x8 o;
#pragma unroll
    for (int jj = 0; jj < 8; ++jj) o[jj] = T[(tc + jj) * 72 + el];
    *(f16x8*)&Vt[hb + (size_t)el * 2048 + t0 + tc] = o;
  }
}

// ---------------------------------------------------------------------------
// GEMM4: C[M,N] = A[M,K] x Bt[N,K]^T, BM=256, BN=128, BK=64.
// 512 threads = 8 waves as 4M x 2N; per-wave output 64x64 (16 frags).
// Per K-tile: 3 barriers, two 16-MFMA clusters; counted vmcnt(6).
// MODE 0: scatter f16 -> Q/K/V [B,H,T,HD]
// MODE 1: +bias, relu -> outH f16 [M,N]
// MODE 2: +bias +resid(f16) -> outH f16 [M,N]
template <int MODE>
__global__ __launch_bounds__(512, 1) void gemm4(
    const _Float16* __restrict__ A, const _Float16* __restrict__ Bt,
    int K, int N, int nbx, int cpx,
    const float* __restrict__ bias, const _Float16* __restrict__ residH,
    _Float16* __restrict__ outH,
    _Float16* __restrict__ outQ, _Float16* __restrict__ outKp,
    _Float16* __restrict__ outV) {
  __shared__ _Float16 As[2][2][128 * 64];
  __shared__ _Float16 Bs[2][128 * 64];
  const int tid = threadIdx.x;
  const int lane = tid & 63;
  const int w = tid >> 6;                  // 0..7
  const int wr = w >> 1, wc = w & 1;       // 4M x 2N
  const int lr = lane & 15, g = lane >> 4;
  const int o = (blockIdx.x & 7) * cpx + (blockIdx.x >> 3);
  const int m0 = (o / nbx) * 256, n0 = (o % nbx) * 128;
  const int NT = K >> 6;

  const _Float16* Ab = A + (size_t)m0 * K;
  const _Float16* Bb = Bt + (size_t)n0 * K;

  f32x4 acc[4][4] = {};

  auto STG = [&](const _Float16* src, _Float16* dst) {
#pragma unroll
    for (int it = 0; it < 2; ++it) {
      const int c = it * 512 + tid;        // chunk 0..1023 (16B)
      const int r = c >> 3;                // row 0..127
      const int ts = (c & 7) ^ (r & 7);    // swizzled k-chunk
      gl2lds16(src + (size_t)r * K + ts * 8, dst + c * 8);
    }
  };

  // ---- prologue: tiles 0 and 1 ----
  STG(Ab, &As[0][0][0]);
  STG(Ab + 128 * (size_t)K, &As[0][1][0]);
  STG(Bb, &Bs[0][0]);
  STG(Ab + 64, &As[1][0][0]);
  STG(Ab + 128 * (size_t)K + 64, &As[1][1][0]);
  STG(Bb + 64, &Bs[1][0]);
  asm volatile("s_waitcnt vmcnt(6)" ::: "memory");
  FENCE_BAR;

  f16x8 af[4][2], bfL[2][2], bfH[2][2];

  for (int t = 0; t < NT; ++t) {
    const int b = t & 1;
    // ---- R0: all A frags + B lo frags ----
#pragma unroll
    for (int mf = 0; mf < 4; ++mf) {
      const int rl = (wr & 1) * 64 + mf * 16 + lr;
#pragma unroll
      for (int k2 = 0; k2 < 2; ++k2)
        af[mf][k2] = *(const f16x8*)&As[b][wr >> 1]
            [rl * 64 + (((k2 * 4 + g) ^ (rl & 7)) << 3)];
    }
#pragma unroll
    for (int nf = 0; nf < 2; ++nf) {
      const int rb = wc * 64 + nf * 16 + lr;
#pragma unroll
      for (int k2 = 0; k2 < 2; ++k2)
        bfL[nf][k2] = *(const f16x8*)&Bs[b]
            [rb * 64 + (((k2 * 4 + g) ^ (rb & 7)) << 3)];
    }
    FENCE_BAR;
    // ---- M0: stage A(t+2); read B hi; MMA lo ----
    if (t + 2 < NT) {
      STG(Ab + (size_t)(t + 2) * 64, &As[b][0][0]);
      STG(Ab + 128 * (size_t)K + (size_t)(t + 2) * 64, &As[b][1][0]);
    }
#pragma unroll
    for (int nf = 0; nf < 2; ++nf) {
      const int rb = wc * 64 + (nf + 2) * 16 + lr;
#pragma unroll
      for (int k2 = 0; k2 < 2; ++k2)
        bfH[nf][k2] = *(const f16x8*)&Bs[b]
            [rb * 64 + (((k2 * 4 + g) ^ (rb & 7)) << 3)];
    }
    __builtin_amdgcn_s_setprio(1);
#pragma unroll
    for (int mf = 0; mf < 4; ++mf)
#pragma unroll
      for (int nf = 0; nf < 2; ++nf)
#pragma unroll
        for (int k2 = 0; k2 < 2; ++k2)
          acc[mf][nf] = __builtin_amdgcn_mfma_f32_16x16x32_f16(
              af[mf][k2], bfL[nf][k2], acc[mf][nf], 0, 0, 0);
    __builtin_amdgcn_s_setprio(0);
    FENCE_BAR;
    // ---- M1: stage B(t+2); MMA hi; counted vmcnt ----
    if (t + 2 < NT) STG(Bb + (size_t)(t + 2) * 64, &Bs[b][0]);
    __builtin_amdgcn_s_setprio(1);
#pragma unroll
    for (int mf = 0; mf < 4; ++mf)
#pragma unroll
      for (int nf = 0; nf < 2; ++nf)
#pragma unroll
        for (int k2 = 0; k2 < 2; ++k2)
          acc[mf][nf + 2] = __builtin_amdgcn_mfma_f32_16x16x32_f16(
              af[mf][k2], bfH[nf][k2], acc[mf][nf + 2], 0, 0, 0);
    __builtin_amdgcn_s_setprio(0);
    if (t == NT - 2) {
      asm volatile("s_waitcnt vmcnt(0)" ::: "memory");
    } else if (t < NT - 2) {
      asm volatile("s_waitcnt vmcnt(6)" ::: "memory");
    }
    FENCE_BAR;
  }

  // ---- epilogue ----
#pragma unroll
  for (int mf = 0; mf < 4; ++mf) {
#pragma unroll
    for (int nf = 0; nf < 4; ++nf) {
#pragma unroll
      for (int rr = 0; rr < 4; ++rr) {
        const int row = m0 + wr * 64 + mf * 16 + g * 4 + rr;
        const int col = n0 + wc * 64 + nf * 16 + lr;
        float v = acc[mf][nf][rr];
        if constexpr (MODE == 0) {
          const int qkv = col >> 10;
          const int h = (col >> 6) & 15;
          const int e = col & 63;
          const int bb = row >> 11;
          const int tt = row & 2047;
          const size_t idx = (((size_t)bb * 16 + h) * 2048 + tt) * 64 + e;
          const _Float16 hv = (_Float16)v;
          if (qkv == 0)      outQ[idx] = hv;
          else if (qkv == 1) outKp[idx] = hv;
          else               outV[idx] = hv;
        } else if constexpr (MODE == 1) {
          outH[(size_t)row * N + col] =
              (_Float16)fmaxf(v + bias[col], 0.0f);
        } else {
          outH[(size_t)row * N + col] = (_Float16)(
              v + bias[col] + (float)residH[(size_t)row * N + col]);
        }
      }
    }
  }
}

// ---------------------------------------------------------------------------
// Flash attention fwd, causal, work-balanced (round-11-proven).
// Double-buffer, vmcnt(0)+barrier at top of each unit. Swapped QK^T
// (D[kv][q]); kf/vbf shared across mi; act0 guard; P = 2^s via raw
// v_exp_f32; packed f16x4 P stores; f16 Y.
__global__ __launch_bounds__(256, 2) void attn_fwd9(
    const _Float16* __restrict__ Qg, const _Float16* __restrict__ Kg,
    const _Float16* __restrict__ Vtg, _Float16* __restrict__ Yg) {
  __shared__ _Float16 Ksm[2][64 * 64];   // [buf][kv][e] swizzled chunks
  __shared__ _Float16 Vts[2][64 * 64];   // [buf][e][kv] swizzled chunks
  __shared__ _Float16 Psm[128 * 72];     // [q][kv] pad 72, wave-private rows
  const int tid = threadIdx.x;
  const int lane = tid & 63;
  const int w = tid >> 6;
  const int lr = lane & 15, g = lane >> 4;

  const int bid = blockIdx.x;                  // 0..511
  const int bh  = (bid & 7) * 8 + ((bid >> 3) & 7);
  const int p   = bid >> 6;                    // pair index 0..7
  const int qtA = p, qtB = 15 - p;
  const int njA = 2 * p + 2;
  const int ntot = 34;

  const size_t hbo = (size_t)bh * (2048 * 64);
  const _Float16* Qb = Qg + hbo;
  const _Float16* Kb = Kg + hbo;
  const _Float16* Vb = Vtg + hbo;              // [64][2048]
  _Float16* Yb = Yg + hbo;

  f16x8 qfA[2][2], qfB[2][2];
#pragma unroll
  for (int mi = 0; mi < 2; ++mi) {
    const int rA = qtA * 128 + mi * 64 + w * 16 + lr;
    const int rB = qtB * 128 + mi * 64 + w * 16 + lr;
#pragma unroll
    for (int ss = 0; ss < 2; ++ss) {
      qfA[mi][ss] = *(const f16x8*)&Qb[(size_t)rA * 64 + ss * 32 + g * 8];
      qfB[mi][ss] = *(const f16x8*)&Qb[(size_t)rB * 64 + ss * 32 + g * 8];
    }
  }

  f32x4 accYA[2][4] = {}, accYB[2][4] = {};
  f32x4 accLA[2] = {}, accLB[2] = {};

  f16x8 ones;
#pragma unroll
  for (int i = 0; i < 8; ++i) ones[i] = (_Float16)1.0f;

  auto TK0 = [&](int u) { return (u < njA ? u : u - njA) * 64; };

  auto STAGE = [&](int bufi, int tk0) {
#pragma unroll
    for (int it = 0; it < 2; ++it) {
      const int c = it * 256 + tid;   // 0..511 (16B chunks)
      const int r = c >> 3;           // tile row 0..63
      const int ts = (c & 7) ^ (r & 7);
      gl2lds16(Kb + (size_t)(tk0 + r) * 64 + ts * 8, &Ksm[bufi][c * 8]);
      gl2lds16(Vb + (size_t)r * 2048 + tk0 + ts * 8, &Vts[bufi][c * 8]);
    }
  };

  auto BODY = [&](int bufi, int qbase, int tk0, const f16x8 (&qf)[2][2],
                  f32x4 (&accY)[2][4], f32x4 (&accL)[2]) {
    const _Float16* Ks = Ksm[bufi];
    const _Float16* Vs = Vts[bufi];
    const int qlo0 = qbase + w * 16;
    const int qlo1 = qbase + 64 + w * 16;
    const bool act0 = (tk0 <= qlo0 + 15);       // wave-uniform
    // ---- kf hoist (8 reads, shared by both mi) ----
    f16x8 kf[4][2];
#pragma unroll
    for (int ni = 0; ni < 4; ++ni) {
      const int row = ni * 16 + lr;
#pragma unroll
      for (int kk = 0; kk < 2; ++kk)
        kf[ni][kk] = *(const f16x8*)&Ks[row * 64 + (((kk * 4 + g) ^ (row & 7)) << 3)];
    }
    // ---- QK^T (swapped): s[kv][q] ----
    f32x4 s0[4] = {}, s1[4] = {};
    __builtin_amdgcn_s_setprio(1);
    if (act0) {
#pragma unroll
      for (int ni = 0; ni < 4; ++ni)
#pragma unroll
        for (int kk = 0; kk < 2; ++kk)
          s0[ni] = __builtin_amdgcn_mfma_f32_16x16x32_f16(kf[ni][kk], qf[0][kk], s0[ni], 0, 0, 0);
    }
#pragma unroll
    for (int ni = 0; ni < 4; ++ni)
#pragma unroll
      for (int kk = 0; kk < 2; ++kk)
        s1[ni] = __builtin_amdgcn_mfma_f32_16x16x32_f16(kf[ni][kk], qf[1][kk], s1[ni], 0, 0, 0);
    __builtin_amdgcn_s_setprio(0);
    // ---- causal mask (diagonal tiles only) ----
    if (act0 && tk0 + 63 > qlo0) {
      const int qa = qlo0 + lr;
#pragma unroll
      for (int ni = 0; ni < 4; ++ni)
#pragma unroll
        for (int r = 0; r < 4; ++r)
          if (tk0 + ni * 16 + g * 4 + r > qa) s0[ni][r] = -3.0e38f;
    }
    if (tk0 + 63 > qlo1) {
      const int qa = qlo1 + lr;
#pragma unroll
      for (int ni = 0; ni < 4; ++ni)
#pragma unroll
        for (int r = 0; r < 4; ++r)
          if (tk0 + ni * 16 + g * 4 + r > qa) s1[ni][r] = -3.0e38f;
    }
    // ---- P = 2^s via raw v_exp_f32; packed f16x4 (b64) stores ----
    const int prow0 = w * 16 + lr;
    const int prow1 = 64 + w * 16 + lr;
    if (act0) {
#pragma unroll
      for (int ni = 0; ni < 4; ++ni) {
        auto a = __builtin_amdgcn_cvt_pkrtz(__builtin_amdgcn_exp2f(s0[ni][0]),
                                            __builtin_amdgcn_exp2f(s0[ni][1]));
        auto b = __builtin_amdgcn_cvt_pkrtz(__builtin_amdgcn_exp2f(s0[ni][2]),
                                            __builtin_amdgcn_exp2f(s0[ni][3]));
        f16x4 pk4;
        pk4[0] = a[0]; pk4[1] = a[1]; pk4[2] = b[0]; pk4[3] = b[1];
        *(f16x4*)&Psm[prow0 * 72 + ni * 16 + g * 4] = pk4;
      }
    }
#pragma unroll
    for (int ni = 0; ni < 4; ++ni) {
      auto a = __builtin_amdgcn_cvt_pkrtz(__builtin_amdgcn_exp2f(s1[ni][0]),
                                          __builtin_amdgcn_exp2f(s1[ni][1]));
      auto b = __builtin_amdgcn_cvt_pkrtz(__builtin_amdgcn_exp2f(s1[ni][2]),
                                          __builtin_amdgcn_exp2f(s1[ni][3]));
      f16x4 pk4;
      pk4[0] = a[0]; pk4[1] = a[1]; pk4[2] = b[0]; pk4[3] = b[1];
      *(f16x4*)&Psm[prow1 * 72 + ni * 16 + g * 4] = pk4;
    }
    // ---- PV: vbf shared across mi ----
    __builtin_amdgcn_s_setprio(1);
#pragma unroll
    for (int ss = 0; ss < 2; ++ss) {
      f16x8 pa0 = {};
      f16x8 pa1 = *(const f16x8*)&Psm[prow1 * 72 + ss * 32 + g * 8];
      if (act0) pa0 = *(const f16x8*)&Psm[prow0 * 72 + ss * 32 + g * 8];
      if (act0) accL[0] = __builtin_amdgcn_mfma_f32_16x16x32_f16(pa0, ones, accL[0], 0, 0, 0);
      accL[1] = __builtin_amdgcn_mfma_f32_16x16x32_f16(pa1, ones, accL[1], 0, 0, 0);
#pragma unroll
      for (int ne = 0; ne < 4; ++ne) {
        const int vrow = ne * 16 + lr;
        const f16x8 vbf = *(const f16x8*)&Vs[vrow * 64 + (((ss * 4 + g) ^ (vrow & 7)) << 3)];
        if (act0) accY[0][ne] = __builtin_amdgcn_mfma_f32_16x16x32_f16(pa0, vbf, accY[0][ne], 0, 0, 0);
        accY[1][ne] = __builtin_amdgcn_mfma_f32_16x16x32_f16(pa1, vbf, accY[1][ne], 0, 0, 0);
      }
    }
    __builtin_amdgcn_s_setprio(0);
  };

  // ---- proven loop: stage(0); per-unit {vmcnt(0); barrier; stage next;
  // body} ----
  STAGE(0, TK0(0));
  for (int u = 0; u < ntot; ++u) {
    asm volatile("s_waitcnt vmcnt(0)" ::: "memory");
    __builtin_amdgcn_s_barrier();
    __builtin_amdgcn_sched_barrier(0xF);
    const int cur = u & 1;
    if (u + 1 < ntot) STAGE(cur ^ 1, TK0(u + 1));
    if (u < njA) BODY(cur, qtA * 128, u * 64, qfA, accYA, accLA);
    else         BODY(cur, qtB * 128, (u - njA) * 64, qfB, accYB, accLB);
  }

  // ---- epilogue ----
#pragma unroll
  for (int mi = 0; mi < 2; ++mi)
#pragma unroll
    for (int r = 0; r < 4; ++r) {
      const float invA = 1.0f / accLA[mi][r];
      const float invB = 1.0f / accLB[mi][r];
      const int qaA = qtA * 128 + mi * 64 + w * 16 + g * 4 + r;
      const int qaB = qtB * 128 + mi * 64 + w * 16 + g * 4 + r;
#pragma unroll
      for (int ne = 0; ne < 4; ++ne) {
        Yb[(size_t)qaA * 64 + ne * 16 + lr] = (_Float16)(accYA[mi][ne][r] * invA);
        Yb[(size_t)qaB * 64 + ne * 16 + lr] = (_Float16)(accYB[mi][ne][r] * invB);
      }
    }
}

// ---------------------------------------------------------------------------
// LN1: X1 = LN(gather(Y f16) + Xh f16); writes f16. 1 block per row.
__global__ __launch_bounds__(256) void ln1_fused(
    const _Float16* __restrict__ Yh, const _Float16* __restrict__ Xh,
    const float* __restrict__ gam, const float* __restrict__ bet,
    _Float16* __restrict__ X1h) {
  const int row = blockIdx.x;
  const int b = row >> 11, t = row & 2047;
  const int tid = threadIdx.x;
  const int d0 = tid * 4;
  const int h = d0 >> 6, e = d0 & 63;
  const f16x4 y4 = *(const f16x4*)&Yh[(((size_t)b * 16 + h) * 2048 + t) * 64 + e];
  const f16x4 x4 = *(const f16x4*)&Xh[(size_t)row * 1024 + d0];
  float v0 = (float)y4[0] + (float)x4[0], v1 = (float)y4[1] + (float)x4[1];
  float v2 = (float)y4[2] + (float)x4[2], v3 = (float)y4[3] + (float)x4[3];
  float s = v0 + v1 + v2 + v3;
  float q = v0 * v0 + v1 * v1 + v2 * v2 + v3 * v3;
  for (int off = 32; off; off >>= 1) { s += __shfl_xor(s, off); q += __shfl_xor(q, off); }
  __shared__ float red[8];
  const int w = tid >> 6;
  if ((tid & 63) == 0) { red[w] = s; red[4 + w] = q; }
  __syncthreads();
  s = red[0] + red[1] + red[2] + red[3];
  q = red[4] + red[5] + red[6] + red[7];
  const float mean = s * (1.f / 1024.f);
  const float rstd = rsqrtf(q * (1.f / 1024.f) - mean * mean + 1e-5f);
  const float4 G = *(const float4*)&gam[d0];
  const float4 Bv = *(const float4*)&bet[d0];
  f16x4 oh;
  oh[0] = (_Float16)((v0 - mean) * rstd * G.x + Bv.x);
  oh[1] = (_Float16)((v1 - mean) * rstd * G.y + Bv.y);
  oh[2] = (_Float16)((v2 - mean) * rstd * G.z + Bv.z);
  oh[3] = (_Float16)((v3 - mean) * rstd * G.w + Bv.w);
  *(f16x4*)&X1h[(size_t)row * 1024 + d0] = oh;
}

// LN2: out = LN(X2 f16). 1 block per row.
__global__ __launch_bounds__(256) void ln2_kernel(
    const _Float16* __restrict__ In, const float* __restrict__ gam,
    const float* __restrict__ bet, float* __restrict__ Out) {
  const int row = blockIdx.x;
  const int tid = threadIdx.x;
  const int d0 = tid * 4;
  const f16x4 v4 = *(const f16x4*)&In[(size_t)row * 1024 + d0];
  float v0 = (float)v4[0], v1 = (float)v4[1], v2 = (float)v4[2], v3 = (float)v4[3];
  float s = v0 + v1 + v2 + v3;
  float q = v0 * v0 + v1 * v1 + v2 * v2 + v3 * v3;
  for (int off = 32; off; off >>= 1) { s += __shfl_xor(s, off); q += __shfl_xor(q, off); }
  __shared__ float red[8];
  const int w = tid >> 6;
  if ((tid & 63) == 0) { red[w] = s; red[4 + w] = q; }
  __syncthreads();
  s = red[0] + red[1] + red[2] + red[3];
  q = red[4] + red[5] + red[6] + red[7];
  const float mean = s * (1.f / 1024.f);
  const float rstd = rsqrtf(q * (1.f / 1024.f) - mean * mean + 1e-5f);
  const float4 G = *(const float4*)&gam[d0];
  const float4 Bv = *(const float4*)&bet[d0];
  float4 o;
  o.x = (v0 - mean) * rstd * G.x + Bv.x;
  o.y = (v1 - mean) * rstd * G.y + Bv.y;
  o.z = (v2 - mean) * rstd * G.z + Bv.z;
  o.w = (v3 - mean) * rstd * G.w + Bv.w;
  *(float4*)&Out[(size_t)row * 1024 + d0] = o;
}

// ---------------------------------------------------------------------------
extern "C" void kernel_launch(void* const* d_in, const int* in_sizes, int n_in,
                              void* d_out, int out_size, void* d_ws, size_t ws_size,
                              hipStream_t stream) {
  (void)in_sizes; (void)n_in; (void)out_size; (void)ws_size;
  const float* X    = (const float*)d_in[0];
  const float* Wq   = (const float*)d_in[1];
  const float* Wk   = (const float*)d_in[2];
  const float* Wv   = (const float*)d_in[3];
  const float* ln1g = (const float*)d_in[4];
  const float* ln1b = (const float*)d_in[5];
  const float* W1   = (const float*)d_in[6];
  const float* b1   = (const float*)d_in[7];
  const float* W2   = (const float*)d_in[8];
  const float* b2   = (const float*)d_in[9];
  const float* ln2g = (const float*)d_in[10];
  const float* ln2b = (const float*)d_in[11];
  float* out = (float*)d_out;

  // workspace carve (174,063,616 bytes total).
  // Xh now lives until FFN1 (ff1 aliases it); Vt moved to its own region.
  char* ws = (char*)d_ws;
  _Float16* Xh   = (_Float16*)(ws);                     // 16 MiB (live thru LN1)
  _Float16* Qh   = (_Float16*)(ws + 16777216ull);       // 16 MiB
  _Float16* Kh   = (_Float16*)(ws + 33554432ull);       // 16 MiB
  _Float16* Vh   = (_Float16*)(ws + 50331648ull);       // 16 MiB
  _Float16* ff1  = (_Float16*)(ws);                     // 64 MiB alias (FFN1+)
  _Float16* Wqkv = (_Float16*)(ws + 67108864ull);       // 6 MiB  [3072][1024]
  _Float16* W1t  = (_Float16*)(ws + 73400320ull);       // 8 MiB  [4096][1024]
  _Float16* W2t  = (_Float16*)(ws + 81788928ull);       // 8 MiB  [1024][4096]
  _Float16* Yh   = (_Float16*)(ws + 90177536ull);       // 16 MiB (Y f16)
  _Float16* X2h  = (_Float16*)(ws + 90177536ull);       // 16 MiB alias (X2)
  _Float16* Vt   = (_Float16*)(ws + 106954752ull);      // 16 MiB (own region)
  _Float16* X1h  = (_Float16*)(ws + 157286400ull);      // 16 MiB

  // --- fused preprocessing (cvt X + all weight transposes, 1 launch) ---
  preprocess<<<dim3(6912), dim3(256), 0, stream>>>(
      X, Xh, Wq, Wk, Wv, Wqkv, W1, W1t, W2, W2t);

  // --- QKV projection: [8192,1024] x [1024,3072] -> Q/K/V [B,H,T,HD] ---
  gemm4<0><<<dim3(768), dim3(512), 0, stream>>>(
      Xh, Wqkv, 1024, 3072, 24, 96, nullptr, nullptr, nullptr, Qh, Kh, Vh);

  // --- V -> Vt [bh][e][t] ---
  transpose_v<<<dim3(32, 64), dim3(256), 0, stream>>>(Vh, Vt);

  // --- causal flash attention -> Yh [B,H,T,HD] f16 ---
  attn_fwd9<<<dim3(512), dim3(256), 0, stream>>>(Qh, Kh, Vt, Yh);

  // --- LN1(Y + X) -> X1 (f16), X read as f16 ---
  ln1_fused<<<dim3(8192), dim3(256), 0, stream>>>(Yh, Xh, ln1g, ln1b, X1h);

  // --- FFN1: relu(X1 @ W1 + b1) -> ff1 f16 [8192,4096] (gemm4 structure) ---
  gemm4<1><<<dim3(1024), dim3(512), 0, stream>>>(
      X1h, W1t, 1024, 4096, 32, 128, b1, nullptr, ff1, nullptr, nullptr, nullptr);

  // --- FFN2: ff1 @ W2 + b2 + X1(f16) -> X2 f16 ---
  gemm4<2><<<dim3(256), dim3(512), 0, stream>>>(
      ff1, W2t, 4096, 1024, 8, 32, b2, X1h, X2h, nullptr, nullptr, nullptr);

  // --- LN2(X2) -> out ---
  ln2_kernel<<<dim3(8192), dim3(256), 0, stream>>>(X2h, ln2g, ln2b, out);
}

// Round 13
// 318.808 us; speedup vs baseline: 1.0506x; 1.0506x over previous
//
#include <hip/hip_runtime.h>
#include <cstdint>

// ---------------------------------------------------------------------------
// TransformerBlock: B=4, T=2048, D=1024, H=16, HD=64
// Pipeline: preprocess(1 launch) -> GEMM8(QKV) -> transpose(V) -> flash-attn
//           -> LN1(f16 in) -> GEMM8(FFN1,relu) -> GEMM4(FFN2,+resid) -> LN2
// GEMM8 (BN=256, 8-phase, counted vmcnt) for the wide-N GEMMs (measured
// better B-reuse: FETCH 74 vs 139 MB on FFN1); GEMM4 (BN=128) for FFN2
// (N=1024 -> BN=256 would leave half the CUs idle).
// Attention: log2-domain scores, swapped QK^T, no max tracking, raw v_exp.
// ---------------------------------------------------------------------------

typedef _Float16 f16x8 __attribute__((ext_vector_type(8)));
typedef _Float16 f16x4 __attribute__((ext_vector_type(4)));
typedef float    f32x4 __attribute__((ext_vector_type(4)));

#define DEVI __device__ __forceinline__

typedef __attribute__((address_space(1))) uint32_t gas1_u32;
typedef __attribute__((address_space(3))) uint32_t las3_u32;

// async global->LDS, 16B per lane; LDS dest must be linear (base + lane*16)
DEVI void gl2lds16(const void* g, void* l) {
  __builtin_amdgcn_global_load_lds((gas1_u32*)(uintptr_t)g,
                                   (las3_u32*)(uintptr_t)l, 16, 0, 0);
}

#define FENCE_BAR                                                            \
  __builtin_amdgcn_sched_barrier(0xF);                                       \
  __builtin_amdgcn_s_barrier();                                              \
  __builtin_amdgcn_sched_barrier(0xF);

// ---------------------------------------------------------------------------
// Fused preprocessing (one launch):
//  blocks [0,4096):      X f32 -> Xh f16 (8 elems/thread)
//  blocks [4096,4864):   Wq/Wk/Wv [16 slices each of [1024][64]] -> Wqkv B^T
//  blocks [4864,5888):   W1 [1024][4096] -> W1t [4096][1024]
//  blocks [5888,6912):   W2 [4096][1024] -> W2t [1024][4096]
__global__ __launch_bounds__(256) void preprocess(
    const float* __restrict__ X, _Float16* __restrict__ Xh,
    const float* __restrict__ Wq, const float* __restrict__ Wk,
    const float* __restrict__ Wv, _Float16* __restrict__ Wqkv,
    const float* __restrict__ W1, _Float16* __restrict__ W1t,
    const float* __restrict__ W2, _Float16* __restrict__ W2t) {
  const int idx = blockIdx.x;
  const int tid = threadIdx.x;
  if (idx < 4096) {  // ---- cvt X ----
    const int i = (idx * 256 + tid) * 8;
    float4 a = *(const float4*)&X[i];
    float4 b = *(const float4*)&X[i + 4];
    f16x8 o;
    o[0] = (_Float16)a.x; o[1] = (_Float16)a.y; o[2] = (_Float16)a.z; o[3] = (_Float16)a.w;
    o[4] = (_Float16)b.x; o[5] = (_Float16)b.y; o[6] = (_Float16)b.z; o[7] = (_Float16)b.w;
    *(f16x8*)&Xh[i] = o;
    return;
  }
  __shared__ _Float16 T[64 * 72];
  const float* src;
  _Float16* dst;
  int k0, rowbase, stride, dstK;
  float scale = 1.0f;
  if (idx < 4864) {            // ---- Wq/Wk/Wv -> Wqkv ----
    const int j = idx - 4096;  // 0..767
    const int z = j >> 4;      // 0..47
    const int which = z >> 4;  // 0..2
    const int slice = z & 15;
    src = ((which == 0) ? Wq : (which == 1) ? Wk : Wv) + (size_t)slice * 65536;
    scale = (which == 0) ? 0.18033688011112042f : 1.0f;  // log2e/8
    k0 = (j & 15) * 64;
    rowbase = which * 1024 + slice * 64;
    stride = 64; dstK = 1024; dst = Wqkv;
  } else if (idx < 5888) {     // ---- W1 -> W1t ----
    const int j = idx - 4864;  // 0..1023
    src = W1 + (j >> 4) * 64;
    k0 = (j & 15) * 64;
    rowbase = (j >> 4) * 64;
    stride = 4096; dstK = 1024; dst = W1t;
  } else {                     // ---- W2 -> W2t ----
    const int j = idx - 5888;  // 0..1023
    src = W2 + (j >> 6) * 64;
    k0 = (j & 63) * 64;
    rowbase = (j >> 6) * 64;
    stride = 1024; dstK = 4096; dst = W2t;
  }
#pragma unroll
  for (int p = 0; p < 4; ++p) {
    int c = p * 256 + tid;           // 0..1023
    int kl = c >> 4;                 // 0..63
    int nl = (c & 15) * 4;           // 0..60
    float4 v = *(const float4*)&src[(size_t)(k0 + kl) * stride + nl];
    T[(nl + 0) * 72 + kl] = (_Float16)(v.x * scale);
    T[(nl + 1) * 72 + kl] = (_Float16)(v.y * scale);
    T[(nl + 2) * 72 + kl] = (_Float16)(v.z * scale);
    T[(nl + 3) * 72 + kl] = (_Float16)(v.w * scale);
  }
  __syncthreads();
#pragma unroll
  for (int p = 0; p < 2; ++p) {
    int c = p * 256 + tid;           // 0..511
    int nl = c >> 3;                 // 0..63
    int kc = (c & 7) * 8;            // 0..56
    f16x8 vv = *(const f16x8*)&T[nl * 72 + kc];
    *(f16x8*)&dst[(size_t)(rowbase + nl) * dstK + k0 + kc] = vv;
  }
}

// ---------------------------------------------------------------------------
// V [bh][t][e=64] f16  ->  Vt [bh][e=64][t=2048] f16. grid (T/64, BH)
__global__ __launch_bounds__(256) void transpose_v(
    const _Float16* __restrict__ Vh, _Float16* __restrict__ Vt) {
  __shared__ _Float16 T[64 * 72];
  const int t0 = blockIdx.x * 64;
  const size_t hb = (size_t)blockIdx.y * (2048 * 64);
  const int tid = threadIdx.x;
#pragma unroll
  for (int it = 0; it < 2; ++it) {
    const int c = it * 256 + tid;   // 0..511
    const int tl = c >> 3;
    const int ec = (c & 7) * 8;
    *(f16x8*)&T[tl * 72 + ec] =
        *(const f16x8*)&Vh[hb + (size_t)(t0 + tl) * 64 + ec];
  }
  __syncthreads();
#pragma unroll
  for (int it = 0; it < 2; ++it) {
    const int c = it * 256 + tid;
    const int el = c >> 3;
    const int tc = (c & 7) * 8;
    f16x8 o;
#pragma unroll
    for (int jj = 0; jj < 8; ++jj) o[jj] = T[(tc + jj) * 72 + el];
    *(f16x8*)&Vt[hb + (size_t)el * 2048 + t0 + tc] = o;
  }
}

// ---------------------------------------------------------------------------
// GEMM8: BM=256, BN=256, BK=64; 8 waves 2Mx4N; 8-phase schedule with counted
// vmcnt(6). Measured on FFN1: 82 us, 838 TF, FETCH 74 MB (vs gemm4 92.5/139).
// MODE 0: scatter f16 -> Q/K/V [B,H,T,HD]
// MODE 1: +bias, relu -> outH f16 [M,N]
template <int MODE>
__global__ __launch_bounds__(512, 1) void gemm8(
    const _Float16* __restrict__ A, const _Float16* __restrict__ Bt,
    int K, int N, int nbx, int cpx,
    const float* __restrict__ bias, _Float16* __restrict__ outH,
    _Float16* __restrict__ outQ, _Float16* __restrict__ outKp,
    _Float16* __restrict__ outV) {
  __shared__ _Float16 As[2][2][128 * 64];
  __shared__ _Float16 Bs[2][2][128 * 64];
  const int tid = threadIdx.x;
  const int lane = tid & 63;
  const int w = tid >> 6;
  const int wr = w >> 2, wc = w & 3;       // 2M x 4N
  const int lr = lane & 15, g = lane >> 4;
  const int o = (blockIdx.x & 7) * cpx + (blockIdx.x >> 3);
  const int m0 = (o / nbx) * 256, n0 = (o % nbx) * 256;
  const int NT = K >> 6;

  const _Float16* Ab = A + (size_t)m0 * K;
  const _Float16* Bb = Bt + (size_t)n0 * K;

  f32x4 acc[8][4] = {};

  auto STG = [&](const _Float16* src, _Float16* dst) {
#pragma unroll
    for (int it = 0; it < 2; ++it) {
      const int c = it * 512 + tid;
      const int r = c >> 3;
      const int ts = (c & 7) ^ (r & 7);
      gl2lds16(src + (size_t)r * K + ts * 8, dst + c * 8);
    }
  };

  STG(Ab, &As[0][0][0]);
  STG(Ab + 128 * (size_t)K, &As[0][1][0]);
  STG(Bb, &Bs[0][0][0]);
  STG(Bb + 128 * (size_t)K, &Bs[0][1][0]);
  STG(Ab + 64, &As[1][0][0]);
  STG(Ab + 128 * (size_t)K + 64, &As[1][1][0]);
  STG(Bb + 64, &Bs[1][0][0]);
  asm volatile("s_waitcnt vmcnt(6)" ::: "memory");
  FENCE_BAR;

  f16x8 afA[4][2], afB[4][2], bfL[2][2], bfH[2][2];

#define LDA8_(af, MLO, buf)                                                  \
  _Pragma("unroll") for (int mf = 0; mf < 4; ++mf) {                         \
    const int rl = (MLO + mf) * 16 + lr;                                     \
    _Pragma("unroll") for (int k2 = 0; k2 < 2; ++k2)                         \
      af[mf][k2] = *(const f16x8*)&As[buf][wr][rl * 64 +                     \
                      (((k2 * 4 + g) ^ (rl & 7)) << 3)];                     \
  }
#define LDB8_(bf, NLO, buf)                                                  \
  _Pragma("unroll") for (int nf = 0; nf < 2; ++nf) {                         \
    const int rb = wc * 64 + (NLO + nf) * 16 + lr;                           \
    _Pragma("unroll") for (int k2 = 0; k2 < 2; ++k2)                         \
      bf[nf][k2] = *(const f16x8*)&Bs[buf][rb >> 7][(rb & 127) * 64 +        \
                      (((k2 * 4 + g) ^ (rb & 7)) << 3)];                     \
  }
#define MMA8_(af, bf, MB, NB)                                                \
  __builtin_amdgcn_s_setprio(1);                                             \
  _Pragma("unroll") for (int mf = 0; mf < 4; ++mf)                           \
  _Pragma("unroll") for (int nf = 0; nf < 2; ++nf)                           \
  _Pragma("unroll") for (int k2 = 0; k2 < 2; ++k2)                           \
    acc[(MB) + mf][(NB) + nf] = __builtin_amdgcn_mfma_f32_16x16x32_f16(      \
        af[mf][k2], bf[nf][k2], acc[(MB) + mf][(NB) + nf], 0, 0, 0);         \
  __builtin_amdgcn_s_setprio(0);

  for (int t = 0; t < NT; ++t) {
    const int cur = t & 1, nxt = cur ^ 1;
    LDA8_(afA, 0, cur);
    LDB8_(bfL, 0, cur);
    if (t + 1 < NT)
      STG(Bb + 128 * (size_t)K + (size_t)(t + 1) * 64, &Bs[nxt][1][0]);
    FENCE_BAR;
    MMA8_(afA, bfL, 0, 0);
    FENCE_BAR;
    LDA8_(afB, 4, cur);
    FENCE_BAR;
    MMA8_(afB, bfL, 4, 0);
    FENCE_BAR;
    LDB8_(bfH, 2, cur);
    if (t + 2 < NT) STG(Ab + (size_t)(t + 2) * 64, &As[cur][0][0]);
    FENCE_BAR;
    MMA8_(afA, bfH, 0, 2);
    FENCE_BAR;
    if (t + 2 < NT) {
      STG(Ab + 128 * (size_t)K + (size_t)(t + 2) * 64, &As[cur][1][0]);
      STG(Bb + (size_t)(t + 2) * 64, &Bs[cur][0][0]);
    }
    if (t == NT - 2) {
      asm volatile("s_waitcnt vmcnt(0)" ::: "memory");
    } else if (t < NT - 2) {
      asm volatile("s_waitcnt vmcnt(6)" ::: "memory");
    }
    FENCE_BAR;
    MMA8_(afB, bfH, 4, 2);
    FENCE_BAR;
  }
#undef LDA8_
#undef LDB8_
#undef MMA8_

  // ---- epilogue ----
#pragma unroll
  for (int mf = 0; mf < 8; ++mf) {
#pragma unroll
    for (int nf = 0; nf < 4; ++nf) {
#pragma unroll
      for (int rr = 0; rr < 4; ++rr) {
        const int row = m0 + wr * 128 + mf * 16 + g * 4 + rr;
        const int col = n0 + wc * 64 + nf * 16 + lr;
        const float v = acc[mf][nf][rr];
        if constexpr (MODE == 0) {
          const int qkv = col >> 10;
          const int h = (col >> 6) & 15;
          const int e = col & 63;
          const int bb = row >> 11;
          const int tt = row & 2047;
          const size_t idx = (((size_t)bb * 16 + h) * 2048 + tt) * 64 + e;
          const _Float16 hv = (_Float16)v;
          if (qkv == 0)      outQ[idx] = hv;
          else if (qkv == 1) outKp[idx] = hv;
          else               outV[idx] = hv;
        } else {
          outH[(size_t)row * N + col] =
              (_Float16)fmaxf(v + bias[col], 0.0f);
        }
      }
    }
  }
}

// ---------------------------------------------------------------------------
// GEMM4 (FFN2 only): BM=256, BN=128, BK=64; 8 waves 4Mx2N; 3 barriers/K-tile,
// two 16-MFMA clusters; counted vmcnt(6). +bias +resid(f16) -> f16.
__global__ __launch_bounds__(512, 1) void gemm4_ffn2(
    const _Float16* __restrict__ A, const _Float16* __restrict__ Bt,
    int K, int N, int nbx, int cpx,
    const float* __restrict__ bias, const _Float16* __restrict__ residH,
    _Float16* __restrict__ outH) {
  __shared__ _Float16 As[2][2][128 * 64];
  __shared__ _Float16 Bs[2][128 * 64];
  const int tid = threadIdx.x;
  const int lane = tid & 63;
  const int w = tid >> 6;                  // 0..7
  const int wr = w >> 1, wc = w & 1;       // 4M x 2N
  const int lr = lane & 15, g = lane >> 4;
  const int o = (blockIdx.x & 7) * cpx + (blockIdx.x >> 3);
  const int m0 = (o / nbx) * 256, n0 = (o % nbx) * 128;
  const int NT = K >> 6;

  const _Float16* Ab = A + (size_t)m0 * K;
  const _Float16* Bb = Bt + (size_t)n0 * K;

  f32x4 acc[4][4] = {};

  auto STG = [&](const _Float16* src, _Float16* dst) {
#pragma unroll
    for (int it = 0; it < 2; ++it) {
      const int c = it * 512 + tid;        // chunk 0..1023 (16B)
      const int r = c >> 3;                // row 0..127
      const int ts = (c & 7) ^ (r & 7);    // swizzled k-chunk
      gl2lds16(src + (size_t)r * K + ts * 8, dst + c * 8);
    }
  };

  STG(Ab, &As[0][0][0]);
  STG(Ab + 128 * (size_t)K, &As[0][1][0]);
  STG(Bb, &Bs[0][0]);
  STG(Ab + 64, &As[1][0][0]);
  STG(Ab + 128 * (size_t)K + 64, &As[1][1][0]);
  STG(Bb + 64, &Bs[1][0]);
  asm volatile("s_waitcnt vmcnt(6)" ::: "memory");
  FENCE_BAR;

  f16x8 af[4][2], bfL[2][2], bfH[2][2];

  for (int t = 0; t < NT; ++t) {
    const int b = t & 1;
#pragma unroll
    for (int mf = 0; mf < 4; ++mf) {
      const int rl = (wr & 1) * 64 + mf * 16 + lr;
#pragma unroll
      for (int k2 = 0; k2 < 2; ++k2)
        af[mf][k2] = *(const f16x8*)&As[b][wr >> 1]
            [rl * 64 + (((k2 * 4 + g) ^ (rl & 7)) << 3)];
    }
#pragma unroll
    for (int nf = 0; nf < 2; ++nf) {
      const int rb = wc * 64 + nf * 16 + lr;
#pragma unroll
      for (int k2 = 0; k2 < 2; ++k2)
        bfL[nf][k2] = *(const f16x8*)&Bs[b]
            [rb * 64 + (((k2 * 4 + g) ^ (rb & 7)) << 3)];
    }
    FENCE_BAR;
    if (t + 2 < NT) {
      STG(Ab + (size_t)(t + 2) * 64, &As[b][0][0]);
      STG(Ab + 128 * (size_t)K + (size_t)(t + 2) * 64, &As[b][1][0]);
    }
#pragma unroll
    for (int nf = 0; nf < 2; ++nf) {
      const int rb = wc * 64 + (nf + 2) * 16 + lr;
#pragma unroll
      for (int k2 = 0; k2 < 2; ++k2)
        bfH[nf][k2] = *(const f16x8*)&Bs[b]
            [rb * 64 + (((k2 * 4 + g) ^ (rb & 7)) << 3)];
    }
    __builtin_amdgcn_s_setprio(1);
#pragma unroll
    for (int mf = 0; mf < 4; ++mf)
#pragma unroll
      for (int nf = 0; nf < 2; ++nf)
#pragma unroll
        for (int k2 = 0; k2 < 2; ++k2)
          acc[mf][nf] = __builtin_amdgcn_mfma_f32_16x16x32_f16(
              af[mf][k2], bfL[nf][k2], acc[mf][nf], 0, 0, 0);
    __builtin_amdgcn_s_setprio(0);
    FENCE_BAR;
    if (t + 2 < NT) STG(Bb + (size_t)(t + 2) * 64, &Bs[b][0]);
    __builtin_amdgcn_s_setprio(1);
#pragma unroll
    for (int mf = 0; mf < 4; ++mf)
#pragma unroll
      for (int nf = 0; nf < 2; ++nf)
#pragma unroll
        for (int k2 = 0; k2 < 2; ++k2)
          acc[mf][nf + 2] = __builtin_amdgcn_mfma_f32_16x16x32_f16(
              af[mf][k2], bfH[nf][k2], acc[mf][nf + 2], 0, 0, 0);
    __builtin_amdgcn_s_setprio(0);
    if (t == NT - 2) {
      asm volatile("s_waitcnt vmcnt(0)" ::: "memory");
    } else if (t < NT - 2) {
      asm volatile("s_waitcnt vmcnt(6)" ::: "memory");
    }
    FENCE_BAR;
  }

#pragma unroll
  for (int mf = 0; mf < 4; ++mf) {
#pragma unroll
    for (int nf = 0; nf < 4; ++nf) {
#pragma unroll
      for (int rr = 0; rr < 4; ++rr) {
        const int row = m0 + wr * 64 + mf * 16 + g * 4 + rr;
        const int col = n0 + wc * 64 + nf * 16 + lr;
        outH[(size_t)row * N + col] = (_Float16)(
            acc[mf][nf][rr] + bias[col] +
            (float)residH[(size_t)row * N + col]);
      }
    }
  }
}

// ---------------------------------------------------------------------------
// Flash attention fwd, causal, work-balanced (round-11-proven).
// Double-buffer, vmcnt(0)+barrier at top of each unit. Swapped QK^T
// (D[kv][q]); kf/vbf shared across mi; act0 guard; P = 2^s via raw
// v_exp_f32; packed f16x4 P stores; f16 Y.
__global__ __launch_bounds__(256, 2) void attn_fwd9(
    const _Float16* __restrict__ Qg, const _Float16* __restrict__ Kg,
    const _Float16* __restrict__ Vtg, _Float16* __restrict__ Yg) {
  __shared__ _Float16 Ksm[2][64 * 64];   // [buf][kv][e] swizzled chunks
  __shared__ _Float16 Vts[2][64 * 64];   // [buf][e][kv] swizzled chunks
  __shared__ _Float16 Psm[128 * 72];     // [q][kv] pad 72, wave-private rows
  const int tid = threadIdx.x;
  const int lane = tid & 63;
  const int w = tid >> 6;
  const int lr = lane & 15, g = lane >> 4;

  const int bid = blockIdx.x;                  // 0..511
  const int bh  = (bid & 7) * 8 + ((bid >> 3) & 7);
  const int p   = bid >> 6;                    // pair index 0..7
  const int qtA = p, qtB = 15 - p;
  const int njA = 2 * p + 2;
  const int ntot = 34;

  const size_t hbo = (size_t)bh * (2048 * 64);
  const _Float16* Qb = Qg + hbo;
  const _Float16* Kb = Kg + hbo;
  const _Float16* Vb = Vtg + hbo;              // [64][2048]
  _Float16* Yb = Yg + hbo;

  f16x8 qfA[2][2], qfB[2][2];
#pragma unroll
  for (int mi = 0; mi < 2; ++mi) {
    const int rA = qtA * 128 + mi * 64 + w * 16 + lr;
    const int rB = qtB * 128 + mi * 64 + w * 16 + lr;
#pragma unroll
    for (int ss = 0; ss < 2; ++ss) {
      qfA[mi][ss] = *(const f16x8*)&Qb[(size_t)rA * 64 + ss * 32 + g * 8];
      qfB[mi][ss] = *(const f16x8*)&Qb[(size_t)rB * 64 + ss * 32 + g * 8];
    }
  }

  f32x4 accYA[2][4] = {}, accYB[2][4] = {};
  f32x4 accLA[2] = {}, accLB[2] = {};

  f16x8 ones;
#pragma unroll
  for (int i = 0; i < 8; ++i) ones[i] = (_Float16)1.0f;

  auto TK0 = [&](int u) { return (u < njA ? u : u - njA) * 64; };

  auto STAGE = [&](int bufi, int tk0) {
#pragma unroll
    for (int it = 0; it < 2; ++it) {
      const int c = it * 256 + tid;   // 0..511 (16B chunks)
      const int r = c >> 3;           // tile row 0..63
      const int ts = (c & 7) ^ (r & 7);
      gl2lds16(Kb + (size_t)(tk0 + r) * 64 + ts * 8, &Ksm[bufi][c * 8]);
      gl2lds16(Vb + (size_t)r * 2048 + tk0 + ts * 8, &Vts[bufi][c * 8]);
    }
  };

  auto BODY = [&](int bufi, int qbase, int tk0, const f16x8 (&qf)[2][2],
                  f32x4 (&accY)[2][4], f32x4 (&accL)[2]) {
    const _Float16* Ks = Ksm[bufi];
    const _Float16* Vs = Vts[bufi];
    const int qlo0 = qbase + w * 16;
    const int qlo1 = qbase + 64 + w * 16;
    const bool act0 = (tk0 <= qlo0 + 15);       // wave-uniform
    f16x8 kf[4][2];
#pragma unroll
    for (int ni = 0; ni < 4; ++ni) {
      const int row = ni * 16 + lr;
#pragma unroll
      for (int kk = 0; kk < 2; ++kk)
        kf[ni][kk] = *(const f16x8*)&Ks[row * 64 + (((kk * 4 + g) ^ (row & 7)) << 3)];
    }
    f32x4 s0[4] = {}, s1[4] = {};
    __builtin_amdgcn_s_setprio(1);
    if (act0) {
#pragma unroll
      for (int ni = 0; ni < 4; ++ni)
#pragma unroll
        for (int kk = 0; kk < 2; ++kk)
          s0[ni] = __builtin_amdgcn_mfma_f32_16x16x32_f16(kf[ni][kk], qf[0][kk], s0[ni], 0, 0, 0);
    }
#pragma unroll
    for (int ni = 0; ni < 4; ++ni)
#pragma unroll
      for (int kk = 0; kk < 2; ++kk)
        s1[ni] = __builtin_amdgcn_mfma_f32_16x16x32_f16(kf[ni][kk], qf[1][kk], s1[ni], 0, 0, 0);
    __builtin_amdgcn_s_setprio(0);
    if (act0 && tk0 + 63 > qlo0) {
      const int qa = qlo0 + lr;
#pragma unroll
      for (int ni = 0; ni < 4; ++ni)
#pragma unroll
        for (int r = 0; r < 4; ++r)
          if (tk0 + ni * 16 + g * 4 + r > qa) s0[ni][r] = -3.0e38f;
    }
    if (tk0 + 63 > qlo1) {
      const int qa = qlo1 + lr;
#pragma unroll
      for (int ni = 0; ni < 4; ++ni)
#pragma unroll
        for (int r = 0; r < 4; ++r)
          if (tk0 + ni * 16 + g * 4 + r > qa) s1[ni][r] = -3.0e38f;
    }
    const int prow0 = w * 16 + lr;
    const int prow1 = 64 + w * 16 + lr;
    if (act0) {
#pragma unroll
      for (int ni = 0; ni < 4; ++ni) {
        auto a = __builtin_amdgcn_cvt_pkrtz(__builtin_amdgcn_exp2f(s0[ni][0]),
                                            __builtin_amdgcn_exp2f(s0[ni][1]));
        auto b = __builtin_amdgcn_cvt_pkrtz(__builtin_amdgcn_exp2f(s0[ni][2]),
                                            __builtin_amdgcn_exp2f(s0[ni][3]));
        f16x4 pk4;
        pk4[0] = a[0]; pk4[1] = a[1]; pk4[2] = b[0]; pk4[3] = b[1];
        *(f16x4*)&Psm[prow0 * 72 + ni * 16 + g * 4] = pk4;
      }
    }
#pragma unroll
    for (int ni = 0; ni < 4; ++ni) {
      auto a = __builtin_amdgcn_cvt_pkrtz(__builtin_amdgcn_exp2f(s1[ni][0]),
                                          __builtin_amdgcn_exp2f(s1[ni][1]));
      auto b = __builtin_amdgcn_cvt_pkrtz(__builtin_amdgcn_exp2f(s1[ni][2]),
                                          __builtin_amdgcn_exp2f(s1[ni][3]));
      f16x4 pk4;
      pk4[0] = a[0]; pk4[1] = a[1]; pk4[2] = b[0]; pk4[3] = b[1];
      *(f16x4*)&Psm[prow1 * 72 + ni * 16 + g * 4] = pk4;
    }
    __builtin_amdgcn_s_setprio(1);
#pragma unroll
    for (int ss = 0; ss < 2; ++ss) {
      f16x8 pa0 = {};
      f16x8 pa1 = *(const f16x8*)&Psm[prow1 * 72 + ss * 32 + g * 8];
      if (act0) pa0 = *(const f16x8*)&Psm[prow0 * 72 + ss * 32 + g * 8];
      if (act0) accL[0] = __builtin_amdgcn_mfma_f32_16x16x32_f16(pa0, ones, accL[0], 0, 0, 0);
      accL[1] = __builtin_amdgcn_mfma_f32_16x16x32_f16(pa1, ones, accL[1], 0, 0, 0);
#pragma unroll
      for (int ne = 0; ne < 4; ++ne) {
        const int vrow = ne * 16 + lr;
        const f16x8 vbf = *(const f16x8*)&Vs[vrow * 64 + (((ss * 4 + g) ^ (vrow & 7)) << 3)];
        if (act0) accY[0][ne] = __builtin_amdgcn_mfma_f32_16x16x32_f16(pa0, vbf, accY[0][ne], 0, 0, 0);
        accY[1][ne] = __builtin_amdgcn_mfma_f32_16x16x32_f16(pa1, vbf, accY[1][ne], 0, 0, 0);
      }
    }
    __builtin_amdgcn_s_setprio(0);
  };

  STAGE(0, TK0(0));
  for (int u = 0; u < ntot; ++u) {
    asm volatile("s_waitcnt vmcnt(0)" ::: "memory");
    __builtin_amdgcn_s_barrier();
    __builtin_amdgcn_sched_barrier(0xF);
    const int cur = u & 1;
    if (u + 1 < ntot) STAGE(cur ^ 1, TK0(u + 1));
    if (u < njA) BODY(cur, qtA * 128, u * 64, qfA, accYA, accLA);
    else         BODY(cur, qtB * 128, (u - njA) * 64, qfB, accYB, accLB);
  }

#pragma unroll
  for (int mi = 0; mi < 2; ++mi)
#pragma unroll
    for (int r = 0; r < 4; ++r) {
      const float invA = 1.0f / accLA[mi][r];
      const float invB = 1.0f / accLB[mi][r];
      const int qaA = qtA * 128 + mi * 64 + w * 16 + g * 4 + r;
      const int qaB = qtB * 128 + mi * 64 + w * 16 + g * 4 + r;
#pragma unroll
      for (int ne = 0; ne < 4; ++ne) {
        Yb[(size_t)qaA * 64 + ne * 16 + lr] = (_Float16)(accYA[mi][ne][r] * invA);
        Yb[(size_t)qaB * 64 + ne * 16 + lr] = (_Float16)(accYB[mi][ne][r] * invB);
      }
    }
}

// ---------------------------------------------------------------------------
// LN1: X1 = LN(gather(Y f16) + Xh f16); writes f16. 1 block per row.
__global__ __launch_bounds__(256) void ln1_fused(
    const _Float16* __restrict__ Yh, const _Float16* __restrict__ Xh,
    const float* __restrict__ gam, const float* __restrict__ bet,
    _Float16* __restrict__ X1h) {
  const int row = blockIdx.x;
  const int b = row >> 11, t = row & 2047;
  const int tid = threadIdx.x;
  const int d0 = tid * 4;
  const int h = d0 >> 6, e = d0 & 63;
  const f16x4 y4 = *(const f16x4*)&Yh[(((size_t)b * 16 + h) * 2048 + t) * 64 + e];
  const f16x4 x4 = *(const f16x4*)&Xh[(size_t)row * 1024 + d0];
  float v0 = (float)y4[0] + (float)x4[0], v1 = (float)y4[1] + (float)x4[1];
  float v2 = (float)y4[2] + (float)x4[2], v3 = (float)y4[3] + (float)x4[3];
  float s = v0 + v1 + v2 + v3;
  float q = v0 * v0 + v1 * v1 + v2 * v2 + v3 * v3;
  for (int off = 32; off; off >>= 1) { s += __shfl_xor(s, off); q += __shfl_xor(q, off); }
  __shared__ float red[8];
  const int w = tid >> 6;
  if ((tid & 63) == 0) { red[w] = s; red[4 + w] = q; }
  __syncthreads();
  s = red[0] + red[1] + red[2] + red[3];
  q = red[4] + red[5] + red[6] + red[7];
  const float mean = s * (1.f / 1024.f);
  const float rstd = rsqrtf(q * (1.f / 1024.f) - mean * mean + 1e-5f);
  const float4 G = *(const float4*)&gam[d0];
  const float4 Bv = *(const float4*)&bet[d0];
  f16x4 oh;
  oh[0] = (_Float16)((v0 - mean) * rstd * G.x + Bv.x);
  oh[1] = (_Float16)((v1 - mean) * rstd * G.y + Bv.y);
  oh[2] = (_Float16)((v2 - mean) * rstd * G.z + Bv.z);
  oh[3] = (_Float16)((v3 - mean) * rstd * G.w + Bv.w);
  *(f16x4*)&X1h[(size_t)row * 1024 + d0] = oh;
}

// LN2: out = LN(X2 f16). 1 block per row.
__global__ __launch_bounds__(256) void ln2_kernel(
    const _Float16* __restrict__ In, const float* __restrict__ gam,
    const float* __restrict__ bet, float* __restrict__ Out) {
  const int row = blockIdx.x;
  const int tid = threadIdx.x;
  const int d0 = tid * 4;
  const f16x4 v4 = *(const f16x4*)&In[(size_t)row * 1024 + d0];
  float v0 = (float)v4[0], v1 = (float)v4[1], v2 = (float)v4[2], v3 = (float)v4[3];
  float s = v0 + v1 + v2 + v3;
  float q = v0 * v0 + v1 * v1 + v2 * v2 + v3 * v3;
  for (int off = 32; off; off >>= 1) { s += __shfl_xor(s, off); q += __shfl_xor(q, off); }
  __shared__ float red[8];
  const int w = tid >> 6;
  if ((tid & 63) == 0) { red[w] = s; red[4 + w] = q; }
  __syncthreads();
  s = red[0] + red[1] + red[2] + red[3];
  q = red[4] + red[5] + red[6] + red[7];
  const float mean = s * (1.f / 1024.f);
  const float rstd = rsqrtf(q * (1.f / 1024.f) - mean * mean + 1e-5f);
  const float4 G = *(const float4*)&gam[d0];
  const float4 Bv = *(const float4*)&bet[d0];
  float4 o;
  o.x = (v0 - mean) * rstd * G.x + Bv.x;
  o.y = (v1 - mean) * rstd * G.y + Bv.y;
  o.z = (v2 - mean) * rstd * G.z + Bv.z;
  o.w = (v3 - mean) * rstd * G.w + Bv.w;
  *(float4*)&Out[(size_t)row * 1024 + d0] = o;
}

// ---------------------------------------------------------------------------
extern "C" void kernel_launch(void* const* d_in, const int* in_sizes, int n_in,
                              void* d_out, int out_size, void* d_ws, size_t ws_size,
                              hipStream_t stream) {
  (void)in_sizes; (void)n_in; (void)out_size; (void)ws_size;
  const float* X    = (const float*)d_in[0];
  const float* Wq   = (const float*)d_in[1];
  const float* Wk   = (const float*)d_in[2];
  const float* Wv   = (const float*)d_in[3];
  const float* ln1g = (const float*)d_in[4];
  const float* ln1b = (const float*)d_in[5];
  const float* W1   = (const float*)d_in[6];
  const float* b1   = (const float*)d_in[7];
  const float* W2   = (const float*)d_in[8];
  const float* b2   = (const float*)d_in[9];
  const float* ln2g = (const float*)d_in[10];
  const float* ln2b = (const float*)d_in[11];
  float* out = (float*)d_out;

  // workspace carve (174,063,616 bytes total).
  char* ws = (char*)d_ws;
  _Float16* Xh   = (_Float16*)(ws);                     // 16 MiB (live thru LN1)
  _Float16* Qh   = (_Float16*)(ws + 16777216ull);       // 16 MiB
  _Float16* Kh   = (_Float16*)(ws + 33554432ull);       // 16 MiB
  _Float16* Vh   = (_Float16*)(ws + 50331648ull);       // 16 MiB
  _Float16* ff1  = (_Float16*)(ws);                     // 64 MiB alias (FFN1+)
  _Float16* Wqkv = (_Float16*)(ws + 67108864ull);       // 6 MiB  [3072][1024]
  _Float16* W1t  = (_Float16*)(ws + 73400320ull);       // 8 MiB  [4096][1024]
  _Float16* W2t  = (_Float16*)(ws + 81788928ull);       // 8 MiB  [1024][4096]
  _Float16* Yh   = (_Float16*)(ws + 90177536ull);       // 16 MiB (Y f16)
  _Float16* X2h  = (_Float16*)(ws + 90177536ull);       // 16 MiB alias (X2)
  _Float16* Vt   = (_Float16*)(ws + 106954752ull);      // 16 MiB (own region)
  _Float16* X1h  = (_Float16*)(ws + 157286400ull);      // 16 MiB

  // --- fused preprocessing (cvt X + all weight transposes, 1 launch) ---
  preprocess<<<dim3(6912), dim3(256), 0, stream>>>(
      X, Xh, Wq, Wk, Wv, Wqkv, W1, W1t, W2, W2t);

  // --- QKV projection: [8192,1024] x [1024,3072] -> Q/K/V (gemm8, BN=256) ---
  gemm8<0><<<dim3(384), dim3(512), 0, stream>>>(
      Xh, Wqkv, 1024, 3072, 12, 48, nullptr, nullptr, Qh, Kh, Vh);

  // --- V -> Vt [bh][e][t] ---
  transpose_v<<<dim3(32, 64), dim3(256), 0, stream>>>(Vh, Vt);

  // --- causal flash attention -> Yh [B,H,T,HD] f16 ---
  attn_fwd9<<<dim3(512), dim3(256), 0, stream>>>(Qh, Kh, Vt, Yh);

  // --- LN1(Y + X) -> X1 (f16), X read as f16 ---
  ln1_fused<<<dim3(8192), dim3(256), 0, stream>>>(Yh, Xh, ln1g, ln1b, X1h);

  // --- FFN1: relu(X1 @ W1 + b1) -> ff1 f16 (gemm8, BN=256, proven 82 us) ---
  gemm8<1><<<dim3(512), dim3(512), 0, stream>>>(
      X1h, W1t, 1024, 4096, 16, 64, b1, ff1, nullptr, nullptr, nullptr);

  // --- FFN2: ff1 @ W2 + b2 + X1(f16) -> X2 f16 (gemm4, BN=128) ---
  gemm4_ffn2<<<dim3(256), dim3(512), 0, stream>>>(
      ff1, W2t, 4096, 1024, 8, 32, b2, X1h, X2h);

  // --- LN2(X2) -> out ---
  ln2_kernel<<<dim3(8192), dim3(256), 0, stream>>>(X2h, ln2g, ln2b, out);
}

// Round 14
// 317.648 us; speedup vs baseline: 1.0544x; 1.0037x over previous
//
#include <hip/hip_runtime.h>
#include <cstdint>

// ---------------------------------------------------------------------------
// TransformerBlock: B=4, T=2048, D=1024, H=16, HD=64
// Pipeline: preprocess(1 launch) -> GEMM8(QKV) -> transpose(V) -> flash-attn
//           -> LN1(f16 in) -> GEMM8(FFN1,relu) -> GEMM4(FFN2,+resid) -> LN2
// GEMM8: BN=256 8-phase; RELAXED fencing (bare s_barrier; one sched_barrier(0)
// pin per STAGE group; asm vmcnt clobbers are the memory anchors) so the
// compiler can interleave ds_reads with MFMAs across phase boundaries.
// GEMM4 (BN=128) for FFN2. Attention: log2 scores, swapped QK^T, raw v_exp.
// ---------------------------------------------------------------------------

typedef _Float16 f16x8 __attribute__((ext_vector_type(8)));
typedef _Float16 f16x4 __attribute__((ext_vector_type(4)));
typedef float    f32x4 __attribute__((ext_vector_type(4)));

#define DEVI __device__ __forceinline__

typedef __attribute__((address_space(1))) uint32_t gas1_u32;
typedef __attribute__((address_space(3))) uint32_t las3_u32;

// async global->LDS, 16B per lane; LDS dest must be linear (base + lane*16)
DEVI void gl2lds16(const void* g, void* l) {
  __builtin_amdgcn_global_load_lds((gas1_u32*)(uintptr_t)g,
                                   (las3_u32*)(uintptr_t)l, 16, 0, 0);
}

#define FENCE_BAR                                                            \
  __builtin_amdgcn_sched_barrier(0xF);                                       \
  __builtin_amdgcn_s_barrier();                                              \
  __builtin_amdgcn_sched_barrier(0xF);

// ---------------------------------------------------------------------------
// Fused preprocessing (one launch):
//  blocks [0,4096):      X f32 -> Xh f16 (8 elems/thread)
//  blocks [4096,4864):   Wq/Wk/Wv [16 slices each of [1024][64]] -> Wqkv B^T
//  blocks [4864,5888):   W1 [1024][4096] -> W1t [4096][1024]
//  blocks [5888,6912):   W2 [4096][1024] -> W2t [1024][4096]
__global__ __launch_bounds__(256) void preprocess(
    const float* __restrict__ X, _Float16* __restrict__ Xh,
    const float* __restrict__ Wq, const float* __restrict__ Wk,
    const float* __restrict__ Wv, _Float16* __restrict__ Wqkv,
    const float* __restrict__ W1, _Float16* __restrict__ W1t,
    const float* __restrict__ W2, _Float16* __restrict__ W2t) {
  const int idx = blockIdx.x;
  const int tid = threadIdx.x;
  if (idx < 4096) {  // ---- cvt X ----
    const int i = (idx * 256 + tid) * 8;
    float4 a = *(const float4*)&X[i];
    float4 b = *(const float4*)&X[i + 4];
    f16x8 o;
    o[0] = (_Float16)a.x; o[1] = (_Float16)a.y; o[2] = (_Float16)a.z; o[3] = (_Float16)a.w;
    o[4] = (_Float16)b.x; o[5] = (_Float16)b.y; o[6] = (_Float16)b.z; o[7] = (_Float16)b.w;
    *(f16x8*)&Xh[i] = o;
    return;
  }
  __shared__ _Float16 T[64 * 72];
  const float* src;
  _Float16* dst;
  int k0, rowbase, stride, dstK;
  float scale = 1.0f;
  if (idx < 4864) {            // ---- Wq/Wk/Wv -> Wqkv ----
    const int j = idx - 4096;  // 0..767
    const int z = j >> 4;      // 0..47
    const int which = z >> 4;  // 0..2
    const int slice = z & 15;
    src = ((which == 0) ? Wq : (which == 1) ? Wk : Wv) + (size_t)slice * 65536;
    scale = (which == 0) ? 0.18033688011112042f : 1.0f;  // log2e/8
    k0 = (j & 15) * 64;
    rowbase = which * 1024 + slice * 64;
    stride = 64; dstK = 1024; dst = Wqkv;
  } else if (idx < 5888) {     // ---- W1 -> W1t ----
    const int j = idx - 4864;  // 0..1023
    src = W1 + (j >> 4) * 64;
    k0 = (j & 15) * 64;
    rowbase = (j >> 4) * 64;
    stride = 4096; dstK = 1024; dst = W1t;
  } else {                     // ---- W2 -> W2t ----
    const int j = idx - 5888;  // 0..1023
    src = W2 + (j >> 6) * 64;
    k0 = (j & 63) * 64;
    rowbase = (j >> 6) * 64;
    stride = 1024; dstK = 4096; dst = W2t;
  }
#pragma unroll
  for (int p = 0; p < 4; ++p) {
    int c = p * 256 + tid;           // 0..1023
    int kl = c >> 4;                 // 0..63
    int nl = (c & 15) * 4;           // 0..60
    float4 v = *(const float4*)&src[(size_t)(k0 + kl) * stride + nl];
    T[(nl + 0) * 72 + kl] = (_Float16)(v.x * scale);
    T[(nl + 1) * 72 + kl] = (_Float16)(v.y * scale);
    T[(nl + 2) * 72 + kl] = (_Float16)(v.z * scale);
    T[(nl + 3) * 72 + kl] = (_Float16)(v.w * scale);
  }
  __syncthreads();
#pragma unroll
  for (int p = 0; p < 2; ++p) {
    int c = p * 256 + tid;           // 0..511
    int nl = c >> 3;                 // 0..63
    int kc = (c & 7) * 8;            // 0..56
    f16x8 vv = *(const f16x8*)&T[nl * 72 + kc];
    *(f16x8*)&dst[(size_t)(rowbase + nl) * dstK + k0 + kc] = vv;
  }
}

// ---------------------------------------------------------------------------
// V [bh][t][e=64] f16  ->  Vt [bh][e=64][t=2048] f16. grid (T/64, BH)
__global__ __launch_bounds__(256) void transpose_v(
    const _Float16* __restrict__ Vh, _Float16* __restrict__ Vt) {
  __shared__ _Float16 T[64 * 72];
  const int t0 = blockIdx.x * 64;
  const size_t hb = (size_t)blockIdx.y * (2048 * 64);
  const int tid = threadIdx.x;
#pragma unroll
  for (int it = 0; it < 2; ++it) {
    const int c = it * 256 + tid;   // 0..511
    const int tl = c >> 3;
    const int ec = (c & 7) * 8;
    *(f16x8*)&T[tl * 72 + ec] =
        *(const f16x8*)&Vh[hb + (size_t)(t0 + tl) * 64 + ec];
  }
  __syncthreads();
#pragma unroll
  for (int it = 0; it < 2; ++it) {
    const int c = it * 256 + tid;
    const int el = c >> 3;
    const int tc = (c & 7) * 8;
    f16x8 o;
#pragma unroll
    for (int jj = 0; jj < 8; ++jj) o[jj] = T[(tc + jj) * 72 + el];
    *(f16x8*)&Vt[hb + (size_t)el * 2048 + t0 + tc] = o;
  }
}

// ---------------------------------------------------------------------------
// GEMM8: BM=256, BN=256, BK=64; 8 waves 2Mx4N; 8-phase schedule with counted
// vmcnt(6). RELAXED fencing: bare s_barrier at phase ends (compiler may float
// ds_reads/MFMA across); sched_barrier(0) pins each STAGE group's issue
// point; asm vmcnt memory-clobbers anchor all cross-buffer hazards.
// Race audit: stages can't hoist above their sched0 pin nor sink past the
// next vmcnt asm; tile t+1 reads can hoist at most to after vmcnt(6) of tile
// t, where t+1 is provably resident (newest-6 = t+2's stages).
// MODE 0: scatter f16 -> Q/K/V [B,H,T,HD]
// MODE 1: +bias, relu -> outH f16 [M,N]
template <int MODE>
__global__ __launch_bounds__(512, 1) void gemm8(
    const _Float16* __restrict__ A, const _Float16* __restrict__ Bt,
    int K, int N, int nbx, int cpx,
    const float* __restrict__ bias, _Float16* __restrict__ outH,
    _Float16* __restrict__ outQ, _Float16* __restrict__ outKp,
    _Float16* __restrict__ outV) {
  __shared__ _Float16 As[2][2][128 * 64];
  __shared__ _Float16 Bs[2][2][128 * 64];
  const int tid = threadIdx.x;
  const int lane = tid & 63;
  const int w = tid >> 6;
  const int wr = w >> 2, wc = w & 3;       // 2M x 4N
  const int lr = lane & 15, g = lane >> 4;
  const int o = (blockIdx.x & 7) * cpx + (blockIdx.x >> 3);
  const int m0 = (o / nbx) * 256, n0 = (o % nbx) * 256;
  const int NT = K >> 6;

  const _Float16* Ab = A + (size_t)m0 * K;
  const _Float16* Bb = Bt + (size_t)n0 * K;

  f32x4 acc[8][4] = {};

  auto STG = [&](const _Float16* src, _Float16* dst) {
#pragma unroll
    for (int it = 0; it < 2; ++it) {
      const int c = it * 512 + tid;
      const int r = c >> 3;
      const int ts = (c & 7) ^ (r & 7);
      gl2lds16(src + (size_t)r * K + ts * 8, dst + c * 8);
    }
  };

  STG(Ab, &As[0][0][0]);
  STG(Ab + 128 * (size_t)K, &As[0][1][0]);
  STG(Bb, &Bs[0][0][0]);
  STG(Bb + 128 * (size_t)K, &Bs[0][1][0]);
  STG(Ab + 64, &As[1][0][0]);
  STG(Ab + 128 * (size_t)K + 64, &As[1][1][0]);
  STG(Bb + 64, &Bs[1][0][0]);
  asm volatile("s_waitcnt vmcnt(6)" ::: "memory");
  FENCE_BAR;

  f16x8 afA[4][2], afB[4][2], bfL[2][2], bfH[2][2];

#define LDA8_(af, MLO, buf)                                                  \
  _Pragma("unroll") for (int mf = 0; mf < 4; ++mf) {                         \
    const int rl = (MLO + mf) * 16 + lr;                                     \
    _Pragma("unroll") for (int k2 = 0; k2 < 2; ++k2)                         \
      af[mf][k2] = *(const f16x8*)&As[buf][wr][rl * 64 +                     \
                      (((k2 * 4 + g) ^ (rl & 7)) << 3)];                     \
  }
#define LDB8_(bf, NLO, buf)                                                  \
  _Pragma("unroll") for (int nf = 0; nf < 2; ++nf) {                         \
    const int rb = wc * 64 + (NLO + nf) * 16 + lr;                           \
    _Pragma("unroll") for (int k2 = 0; k2 < 2; ++k2)                         \
      bf[nf][k2] = *(const f16x8*)&Bs[buf][rb >> 7][(rb & 127) * 64 +        \
                      (((k2 * 4 + g) ^ (rb & 7)) << 3)];                     \
  }
#define MMA8_(af, bf, MB, NB)                                                \
  __builtin_amdgcn_s_setprio(1);                                             \
  _Pragma("unroll") for (int mf = 0; mf < 4; ++mf)                           \
  _Pragma("unroll") for (int nf = 0; nf < 2; ++nf)                           \
  _Pragma("unroll") for (int k2 = 0; k2 < 2; ++k2)                           \
    acc[(MB) + mf][(NB) + nf] = __builtin_amdgcn_mfma_f32_16x16x32_f16(      \
        af[mf][k2], bf[nf][k2], acc[(MB) + mf][(NB) + nf], 0, 0, 0);         \
  __builtin_amdgcn_s_setprio(0);
#define BAR_ __builtin_amdgcn_s_barrier();
#define SCHED0_ __builtin_amdgcn_sched_barrier(0);

  for (int t = 0; t < NT; ++t) {
    const int cur = t & 1, nxt = cur ^ 1;
    // P0: read A-lo + B-lo; stage B1(t+1) (pinned)
    LDA8_(afA, 0, cur);
    LDB8_(bfL, 0, cur);
    if (t + 1 < NT) {
      SCHED0_;
      STG(Bb + 128 * (size_t)K + (size_t)(t + 1) * 64, &Bs[nxt][1][0]);
    }
    BAR_;
    MMA8_(afA, bfL, 0, 0);
    BAR_;
    // P1: read A-hi
    LDA8_(afB, 4, cur);
    BAR_;
    MMA8_(afB, bfL, 4, 0);
    BAR_;
    // P2: read B-hi; stage A0(t+2) (pinned)
    LDB8_(bfH, 2, cur);
    if (t + 2 < NT) {
      SCHED0_;
      STG(Ab + (size_t)(t + 2) * 64, &As[cur][0][0]);
    }
    BAR_;
    MMA8_(afA, bfH, 0, 2);
    BAR_;
    // P3: stage A1(t+2), B0(t+2) (pinned); counted vmcnt
    if (t + 2 < NT) {
      SCHED0_;
      STG(Ab + 128 * (size_t)K + (size_t)(t + 2) * 64, &As[cur][1][0]);
      STG(Bb + (size_t)(t + 2) * 64, &Bs[cur][0][0]);
    }
    if (t == NT - 2) {
      asm volatile("s_waitcnt vmcnt(0)" ::: "memory");
    } else if (t < NT - 2) {
      asm volatile("s_waitcnt vmcnt(6)" ::: "memory");
    }
    BAR_;
    MMA8_(afB, bfH, 4, 2);
    BAR_;
  }
#undef LDA8_
#undef LDB8_
#undef MMA8_
#undef BAR_
#undef SCHED0_

  // ---- epilogue ----
#pragma unroll
  for (int mf = 0; mf < 8; ++mf) {
#pragma unroll
    for (int nf = 0; nf < 4; ++nf) {
#pragma unroll
      for (int rr = 0; rr < 4; ++rr) {
        const int row = m0 + wr * 128 + mf * 16 + g * 4 + rr;
        const int col = n0 + wc * 64 + nf * 16 + lr;
        const float v = acc[mf][nf][rr];
        if constexpr (MODE == 0) {
          const int qkv = col >> 10;
          const int h = (col >> 6) & 15;
          const int e = col & 63;
          const int bb = row >> 11;
          const int tt = row & 2047;
          const size_t idx = (((size_t)bb * 16 + h) * 2048 + tt) * 64 + e;
          const _Float16 hv = (_Float16)v;
          if (qkv == 0)      outQ[idx] = hv;
          else if (qkv == 1) outKp[idx] = hv;
          else               outV[idx] = hv;
        } else {
          outH[(size_t)row * N + col] =
              (_Float16)fmaxf(v + bias[col], 0.0f);
        }
      }
    }
  }
}

// ---------------------------------------------------------------------------
// GEMM4 (FFN2 only): BM=256, BN=128, BK=64; 8 waves 4Mx2N; 3 barriers/K-tile,
// two 16-MFMA clusters; counted vmcnt(6). +bias +resid(f16) -> f16.
__global__ __launch_bounds__(512, 1) void gemm4_ffn2(
    const _Float16* __restrict__ A, const _Float16* __restrict__ Bt,
    int K, int N, int nbx, int cpx,
    const float* __restrict__ bias, const _Float16* __restrict__ residH,
    _Float16* __restrict__ outH) {
  __shared__ _Float16 As[2][2][128 * 64];
  __shared__ _Float16 Bs[2][128 * 64];
  const int tid = threadIdx.x;
  const int lane = tid & 63;
  const int w = tid >> 6;                  // 0..7
  const int wr = w >> 1, wc = w & 1;       // 4M x 2N
  const int lr = lane & 15, g = lane >> 4;
  const int o = (blockIdx.x & 7) * cpx + (blockIdx.x >> 3);
  const int m0 = (o / nbx) * 256, n0 = (o % nbx) * 128;
  const int NT = K >> 6;

  const _Float16* Ab = A + (size_t)m0 * K;
  const _Float16* Bb = Bt + (size_t)n0 * K;

  f32x4 acc[4][4] = {};

  auto STG = [&](const _Float16* src, _Float16* dst) {
#pragma unroll
    for (int it = 0; it < 2; ++it) {
      const int c = it * 512 + tid;        // chunk 0..1023 (16B)
      const int r = c >> 3;                // row 0..127
      const int ts = (c & 7) ^ (r & 7);    // swizzled k-chunk
      gl2lds16(src + (size_t)r * K + ts * 8, dst + c * 8);
    }
  };

  STG(Ab, &As[0][0][0]);
  STG(Ab + 128 * (size_t)K, &As[0][1][0]);
  STG(Bb, &Bs[0][0]);
  STG(Ab + 64, &As[1][0][0]);
  STG(Ab + 128 * (size_t)K + 64, &As[1][1][0]);
  STG(Bb + 64, &Bs[1][0]);
  asm volatile("s_waitcnt vmcnt(6)" ::: "memory");
  FENCE_BAR;

  f16x8 af[4][2], bfL[2][2], bfH[2][2];

  for (int t = 0; t < NT; ++t) {
    const int b = t & 1;
#pragma unroll
    for (int mf = 0; mf < 4; ++mf) {
      const int rl = (wr & 1) * 64 + mf * 16 + lr;
#pragma unroll
      for (int k2 = 0; k2 < 2; ++k2)
        af[mf][k2] = *(const f16x8*)&As[b][wr >> 1]
            [rl * 64 + (((k2 * 4 + g) ^ (rl & 7)) << 3)];
    }
#pragma unroll
    for (int nf = 0; nf < 2; ++nf) {
      const int rb = wc * 64 + nf * 16 + lr;
#pragma unroll
      for (int k2 = 0; k2 < 2; ++k2)
        bfL[nf][k2] = *(const f16x8*)&Bs[b]
            [rb * 64 + (((k2 * 4 + g) ^ (rb & 7)) << 3)];
    }
    FENCE_BAR;
    if (t + 2 < NT) {
      STG(Ab + (size_t)(t + 2) * 64, &As[b][0][0]);
      STG(Ab + 128 * (size_t)K + (size_t)(t + 2) * 64, &As[b][1][0]);
    }
#pragma unroll
    for (int nf = 0; nf < 2; ++nf) {
      const int rb = wc * 64 + (nf + 2) * 16 + lr;
#pragma unroll
      for (int k2 = 0; k2 < 2; ++k2)
        bfH[nf][k2] = *(const f16x8*)&Bs[b]
            [rb * 64 + (((k2 * 4 + g) ^ (rb & 7)) << 3)];
    }
    __builtin_amdgcn_s_setprio(1);
#pragma unroll
    for (int mf = 0; mf < 4; ++mf)
#pragma unroll
      for (int nf = 0; nf < 2; ++nf)
#pragma unroll
        for (int k2 = 0; k2 < 2; ++k2)
          acc[mf][nf] = __builtin_amdgcn_mfma_f32_16x16x32_f16(
              af[mf][k2], bfL[nf][k2], acc[mf][nf], 0, 0, 0);
    __builtin_amdgcn_s_setprio(0);
    FENCE_BAR;
    if (t + 2 < NT) STG(Bb + (size_t)(t + 2) * 64, &Bs[b][0]);
    __builtin_amdgcn_s_setprio(1);
#pragma unroll
    for (int mf = 0; mf < 4; ++mf)
#pragma unroll
      for (int nf = 0; nf < 2; ++nf)
#pragma unroll
        for (int k2 = 0; k2 < 2; ++k2)
          acc[mf][nf + 2] = __builtin_amdgcn_mfma_f32_16x16x32_f16(
              af[mf][k2], bfH[nf][k2], acc[mf][nf + 2], 0, 0, 0);
    __builtin_amdgcn_s_setprio(0);
    if (t == NT - 2) {
      asm volatile("s_waitcnt vmcnt(0)" ::: "memory");
    } else if (t < NT - 2) {
      asm volatile("s_waitcnt vmcnt(6)" ::: "memory");
    }
    FENCE_BAR;
  }

#pragma unroll
  for (int mf = 0; mf < 4; ++mf) {
#pragma unroll
    for (int nf = 0; nf < 4; ++nf) {
#pragma unroll
      for (int rr = 0; rr < 4; ++rr) {
        const int row = m0 + wr * 64 + mf * 16 + g * 4 + rr;
        const int col = n0 + wc * 64 + nf * 16 + lr;
        outH[(size_t)row * N + col] = (_Float16)(
            acc[mf][nf][rr] + bias[col] +
            (float)residH[(size_t)row * N + col]);
      }
    }
  }
}

// ---------------------------------------------------------------------------
// Flash attention fwd, causal, work-balanced (round-11-proven, unchanged).
__global__ __launch_bounds__(256, 2) void attn_fwd9(
    const _Float16* __restrict__ Qg, const _Float16* __restrict__ Kg,
    const _Float16* __restrict__ Vtg, _Float16* __restrict__ Yg) {
  __shared__ _Float16 Ksm[2][64 * 64];   // [buf][kv][e] swizzled chunks
  __shared__ _Float16 Vts[2][64 * 64];   // [buf][e][kv] swizzled chunks
  __shared__ _Float16 Psm[128 * 72];     // [q][kv] pad 72, wave-private rows
  const int tid = threadIdx.x;
  const int lane = tid & 63;
  const int w = tid >> 6;
  const int lr = lane & 15, g = lane >> 4;

  const int bid = blockIdx.x;                  // 0..511
  const int bh  = (bid & 7) * 8 + ((bid >> 3) & 7);
  const int p   = bid >> 6;                    // pair index 0..7
  const int qtA = p, qtB = 15 - p;
  const int njA = 2 * p + 2;
  const int ntot = 34;

  const size_t hbo = (size_t)bh * (2048 * 64);
  const _Float16* Qb = Qg + hbo;
  const _Float16* Kb = Kg + hbo;
  const _Float16* Vb = Vtg + hbo;              // [64][2048]
  _Float16* Yb = Yg + hbo;

  f16x8 qfA[2][2], qfB[2][2];
#pragma unroll
  for (int mi = 0; mi < 2; ++mi) {
    const int rA = qtA * 128 + mi * 64 + w * 16 + lr;
    const int rB = qtB * 128 + mi * 64 + w * 16 + lr;
#pragma unroll
    for (int ss = 0; ss < 2; ++ss) {
      qfA[mi][ss] = *(const f16x8*)&Qb[(size_t)rA * 64 + ss * 32 + g * 8];
      qfB[mi][ss] = *(const f16x8*)&Qb[(size_t)rB * 64 + ss * 32 + g * 8];
    }
  }

  f32x4 accYA[2][4] = {}, accYB[2][4] = {};
  f32x4 accLA[2] = {}, accLB[2] = {};

  f16x8 ones;
#pragma unroll
  for (int i = 0; i < 8; ++i) ones[i] = (_Float16)1.0f;

  auto TK0 = [&](int u) { return (u < njA ? u : u - njA) * 64; };

  auto STAGE = [&](int bufi, int tk0) {
#pragma unroll
    for (int it = 0; it < 2; ++it) {
      const int c = it * 256 + tid;   // 0..511 (16B chunks)
      const int r = c >> 3;           // tile row 0..63
      const int ts = (c & 7) ^ (r & 7);
      gl2lds16(Kb + (size_t)(tk0 + r) * 64 + ts * 8, &Ksm[bufi][c * 8]);
      gl2lds16(Vb + (size_t)r * 2048 + tk0 + ts * 8, &Vts[bufi][c * 8]);
    }
  };

  auto BODY = [&](int bufi, int qbase, int tk0, const f16x8 (&qf)[2][2],
                  f32x4 (&accY)[2][4], f32x4 (&accL)[2]) {
    const _Float16* Ks = Ksm[bufi];
    const _Float16* Vs = Vts[bufi];
    const int qlo0 = qbase + w * 16;
    const int qlo1 = qbase + 64 + w * 16;
    const bool act0 = (tk0 <= qlo0 + 15);       // wave-uniform
    f16x8 kf[4][2];
#pragma unroll
    for (int ni = 0; ni < 4; ++ni) {
      const int row = ni * 16 + lr;
#pragma unroll
      for (int kk = 0; kk < 2; ++kk)
        kf[ni][kk] = *(const f16x8*)&Ks[row * 64 + (((kk * 4 + g) ^ (row & 7)) << 3)];
    }
    f32x4 s0[4] = {}, s1[4] = {};
    __builtin_amdgcn_s_setprio(1);
    if (act0) {
#pragma unroll
      for (int ni = 0; ni < 4; ++ni)
#pragma unroll
        for (int kk = 0; kk < 2; ++kk)
          s0[ni] = __builtin_amdgcn_mfma_f32_16x16x32_f16(kf[ni][kk], qf[0][kk], s0[ni], 0, 0, 0);
    }
#pragma unroll
    for (int ni = 0; ni < 4; ++ni)
#pragma unroll
      for (int kk = 0; kk < 2; ++kk)
        s1[ni] = __builtin_amdgcn_mfma_f32_16x16x32_f16(kf[ni][kk], qf[1][kk], s1[ni], 0, 0, 0);
    __builtin_amdgcn_s_setprio(0);
    if (act0 && tk0 + 63 > qlo0) {
      const int qa = qlo0 + lr;
#pragma unroll
      for (int ni = 0; ni < 4; ++ni)
#pragma unroll
        for (int r = 0; r < 4; ++r)
          if (tk0 + ni * 16 + g * 4 + r > qa) s0[ni][r] = -3.0e38f;
    }
    if (tk0 + 63 > qlo1) {
      const int qa = qlo1 + lr;
#pragma unroll
      for (int ni = 0; ni < 4; ++ni)
#pragma unroll
        for (int r = 0; r < 4; ++r)
          if (tk0 + ni * 16 + g * 4 + r > qa) s1[ni][r] = -3.0e38f;
    }
    const int prow0 = w * 16 + lr;
    const int prow1 = 64 + w * 16 + lr;
    if (act0) {
#pragma unroll
      for (int ni = 0; ni < 4; ++ni) {
        auto a = __builtin_amdgcn_cvt_pkrtz(__builtin_amdgcn_exp2f(s0[ni][0]),
                                            __builtin_amdgcn_exp2f(s0[ni][1]));
        auto b = __builtin_amdgcn_cvt_pkrtz(__builtin_amdgcn_exp2f(s0[ni][2]),
                                            __builtin_amdgcn_exp2f(s0[ni][3]));
        f16x4 pk4;
        pk4[0] = a[0]; pk4[1] = a[1]; pk4[2] = b[0]; pk4[3] = b[1];
        *(f16x4*)&Psm[prow0 * 72 + ni * 16 + g * 4] = pk4;
      }
    }
#pragma unroll
    for (int ni = 0; ni < 4; ++ni) {
      auto a = __builtin_amdgcn_cvt_pkrtz(__builtin_amdgcn_exp2f(s1[ni][0]),
                                          __builtin_amdgcn_exp2f(s1[ni][1]));
      auto b = __builtin_amdgcn_cvt_pkrtz(__builtin_amdgcn_exp2f(s1[ni][2]),
                                          __builtin_amdgcn_exp2f(s1[ni][3]));
      f16x4 pk4;
      pk4[0] = a[0]; pk4[1] = a[1]; pk4[2] = b[0]; pk4[3] = b[1];
      *(f16x4*)&Psm[prow1 * 72 + ni * 16 + g * 4] = pk4;
    }
    __builtin_amdgcn_s_setprio(1);
#pragma unroll
    for (int ss = 0; ss < 2; ++ss) {
      f16x8 pa0 = {};
      f16x8 pa1 = *(const f16x8*)&Psm[prow1 * 72 + ss * 32 + g * 8];
      if (act0) pa0 = *(const f16x8*)&Psm[prow0 * 72 + ss * 32 + g * 8];
      if (act0) accL[0] = __builtin_amdgcn_mfma_f32_16x16x32_f16(pa0, ones, accL[0], 0, 0, 0);
      accL[1] = __builtin_amdgcn_mfma_f32_16x16x32_f16(pa1, ones, accL[1], 0, 0, 0);
#pragma unroll
      for (int ne = 0; ne < 4; ++ne) {
        const int vrow = ne * 16 + lr;
        const f16x8 vbf = *(const f16x8*)&Vs[vrow * 64 + (((ss * 4 + g) ^ (vrow & 7)) << 3)];
        if (act0) accY[0][ne] = __builtin_amdgcn_mfma_f32_16x16x32_f16(pa0, vbf, accY[0][ne], 0, 0, 0);
        accY[1][ne] = __builtin_amdgcn_mfma_f32_16x16x32_f16(pa1, vbf, accY[1][ne], 0, 0, 0);
      }
    }
    __builtin_amdgcn_s_setprio(0);
  };

  STAGE(0, TK0(0));
  for (int u = 0; u < ntot; ++u) {
    asm volatile("s_waitcnt vmcnt(0)" ::: "memory");
    __builtin_amdgcn_s_barrier();
    __builtin_amdgcn_sched_barrier(0xF);
    const int cur = u & 1;
    if (u + 1 < ntot) STAGE(cur ^ 1, TK0(u + 1));
    if (u < njA) BODY(cur, qtA * 128, u * 64, qfA, accYA, accLA);
    else         BODY(cur, qtB * 128, (u - njA) * 64, qfB, accYB, accLB);
  }

#pragma unroll
  for (int mi = 0; mi < 2; ++mi)
#pragma unroll
    for (int r = 0; r < 4; ++r) {
      const float invA = 1.0f / accLA[mi][r];
      const float invB = 1.0f / accLB[mi][r];
      const int qaA = qtA * 128 + mi * 64 + w * 16 + g * 4 + r;
      const int qaB = qtB * 128 + mi * 64 + w * 16 + g * 4 + r;
#pragma unroll
      for (int ne = 0; ne < 4; ++ne) {
        Yb[(size_t)qaA * 64 + ne * 16 + lr] = (_Float16)(accYA[mi][ne][r] * invA);
        Yb[(size_t)qaB * 64 + ne * 16 + lr] = (_Float16)(accYB[mi][ne][r] * invB);
      }
    }
}

// ---------------------------------------------------------------------------
// LN1: X1 = LN(gather(Y f16) + Xh f16); writes f16. 1 block per row.
__global__ __launch_bounds__(256) void ln1_fused(
    const _Float16* __restrict__ Yh, const _Float16* __restrict__ Xh,
    const float* __restrict__ gam, const float* __restrict__ bet,
    _Float16* __restrict__ X1h) {
  const int row = blockIdx.x;
  const int b = row >> 11, t = row & 2047;
  const int tid = threadIdx.x;
  const int d0 = tid * 4;
  const int h = d0 >> 6, e = d0 & 63;
  const f16x4 y4 = *(const f16x4*)&Yh[(((size_t)b * 16 + h) * 2048 + t) * 64 + e];
  const f16x4 x4 = *(const f16x4*)&Xh[(size_t)row * 1024 + d0];
  float v0 = (float)y4[0] + (float)x4[0], v1 = (float)y4[1] + (float)x4[1];
  float v2 = (float)y4[2] + (float)x4[2], v3 = (float)y4[3] + (float)x4[3];
  float s = v0 + v1 + v2 + v3;
  float q = v0 * v0 + v1 * v1 + v2 * v2 + v3 * v3;
  for (int off = 32; off; off >>= 1) { s += __shfl_xor(s, off); q += __shfl_xor(q, off); }
  __shared__ float red[8];
  const int w = tid >> 6;
  if ((tid & 63) == 0) { red[w] = s; red[4 + w] = q; }
  __syncthreads();
  s = red[0] + red[1] + red[2] + red[3];
  q = red[4] + red[5] + red[6] + red[7];
  const float mean = s * (1.f / 1024.f);
  const float rstd = rsqrtf(q * (1.f / 1024.f) - mean * mean + 1e-5f);
  const float4 G = *(const float4*)&gam[d0];
  const float4 Bv = *(const float4*)&bet[d0];
  f16x4 oh;
  oh[0] = (_Float16)((v0 - mean) * rstd * G.x + Bv.x);
  oh[1] = (_Float16)((v1 - mean) * rstd * G.y + Bv.y);
  oh[2] = (_Float16)((v2 - mean) * rstd * G.z + Bv.z);
  oh[3] = (_Float16)((v3 - mean) * rstd * G.w + Bv.w);
  *(f16x4*)&X1h[(size_t)row * 1024 + d0] = oh;
}

// LN2: out = LN(X2 f16). 1 block per row.
__global__ __launch_bounds__(256) void ln2_kernel(
    const _Float16* __restrict__ In, const float* __restrict__ gam,
    const float* __restrict__ bet, float* __restrict__ Out) {
  const int row = blockIdx.x;
  const int tid = threadIdx.x;
  const int d0 = tid * 4;
  const f16x4 v4 = *(const f16x4*)&In[(size_t)row * 1024 + d0];
  float v0 = (float)v4[0], v1 = (float)v4[1], v2 = (float)v4[2], v3 = (float)v4[3];
  float s = v0 + v1 + v2 + v3;
  float q = v0 * v0 + v1 * v1 + v2 * v2 + v3 * v3;
  for (int off = 32; off; off >>= 1) { s += __shfl_xor(s, off); q += __shfl_xor(q, off); }
  __shared__ float red[8];
  const int w = tid >> 6;
  if ((tid & 63) == 0) { red[w] = s; red[4 + w] = q; }
  __syncthreads();
  s = red[0] + red[1] + red[2] + red[3];
  q = red[4] + red[5] + red[6] + red[7];
  const float mean = s * (1.f / 1024.f);
  const float rstd = rsqrtf(q * (1.f / 1024.f) - mean * mean + 1e-5f);
  const float4 G = *(const float4*)&gam[d0];
  const float4 Bv = *(const float4*)&bet[d0];
  float4 o;
  o.x = (v0 - mean) * rstd * G.x + Bv.x;
  o.y = (v1 - mean) * rstd * G.y + Bv.y;
  o.z = (v2 - mean) * rstd * G.z + Bv.z;
  o.w = (v3 - mean) * rstd * G.w + Bv.w;
  *(float4*)&Out[(size_t)row * 1024 + d0] = o;
}

// ---------------------------------------------------------------------------
extern "C" void kernel_launch(void* const* d_in, const int* in_sizes, int n_in,
                              void* d_out, int out_size, void* d_ws, size_t ws_size,
                              hipStream_t stream) {
  (void)in_sizes; (void)n_in; (void)out_size; (void)ws_size;
  const float* X    = (const float*)d_in[0];
  const float* Wq   = (const float*)d_in[1];
  const float* Wk   = (const float*)d_in[2];
  const float* Wv   = (const float*)d_in[3];
  const float* ln1g = (const float*)d_in[4];
  const float* ln1b = (const float*)d_in[5];
  const float* W1   = (const float*)d_in[6];
  const float* b1   = (const float*)d_in[7];
  const float* W2   = (const float*)d_in[8];
  const float* b2   = (const float*)d_in[9];
  const float* ln2g = (const float*)d_in[10];
  const float* ln2b = (const float*)d_in[11];
  float* out = (float*)d_out;

  // workspace carve (174,063,616 bytes total).
  char* ws = (char*)d_ws;
  _Float16* Xh   = (_Float16*)(ws);                     // 16 MiB (live thru LN1)
  _Float16* Qh   = (_Float16*)(ws + 16777216ull);       // 16 MiB
  _Float16* Kh   = (_Float16*)(ws + 33554432ull);       // 16 MiB
  _Float16* Vh   = (_Float16*)(ws + 50331648ull);       // 16 MiB
  _Float16* ff1  = (_Float16*)(ws);                     // 64 MiB alias (FFN1+)
  _Float16* Wqkv = (_Float16*)(ws + 67108864ull);       // 6 MiB  [3072][1024]
  _Float16* W1t  = (_Float16*)(ws + 73400320ull);       // 8 MiB  [4096][1024]
  _Float16* W2t  = (_Float16*)(ws + 81788928ull);       // 8 MiB  [1024][4096]
  _Float16* Yh   = (_Float16*)(ws + 90177536ull);       // 16 MiB (Y f16)
  _Float16* X2h  = (_Float16*)(ws + 90177536ull);       // 16 MiB alias (X2)
  _Float16* Vt   = (_Float16*)(ws + 106954752ull);      // 16 MiB (own region)
  _Float16* X1h  = (_Float16*)(ws + 157286400ull);      // 16 MiB

  // --- fused preprocessing (cvt X + all weight transposes, 1 launch) ---
  preprocess<<<dim3(6912), dim3(256), 0, stream>>>(
      X, Xh, Wq, Wk, Wv, Wqkv, W1, W1t, W2, W2t);

  // --- QKV projection: [8192,1024] x [1024,3072] -> Q/K/V (gemm8, BN=256) ---
  gemm8<0><<<dim3(384), dim3(512), 0, stream>>>(
      Xh, Wqkv, 1024, 3072, 12, 48, nullptr, nullptr, Qh, Kh, Vh);

  // --- V -> Vt [bh][e][t] ---
  transpose_v<<<dim3(32, 64), dim3(256), 0, stream>>>(Vh, Vt);

  // --- causal flash attention -> Yh [B,H,T,HD] f16 ---
  attn_fwd9<<<dim3(512), dim3(256), 0, stream>>>(Qh, Kh, Vt, Yh);

  // --- LN1(Y + X) -> X1 (f16), X read as f16 ---
  ln1_fused<<<dim3(8192), dim3(256), 0, stream>>>(Yh, Xh, ln1g, ln1b, X1h);

  // --- FFN1: relu(X1 @ W1 + b1) -> ff1 f16 (gemm8 relaxed) ---
  gemm8<1><<<dim3(512), dim3(512), 0, stream>>>(
      X1h, W1t, 1024, 4096, 16, 64, b1, ff1, nullptr, nullptr, nullptr);

  // --- FFN2: ff1 @ W2 + b2 + X1(f16) -> X2 f16 (gemm4, BN=128) ---
  gemm4_ffn2<<<dim3(256), dim3(512), 0, stream>>>(
      ff1, W2t, 4096, 1024, 8, 32, b2, X1h, X2h);

  // --- LN2(X2) -> out ---
  ln2_kernel<<<dim3(8192), dim3(256), 0, stream>>>(X2h, ln2g, ln2b, out);
}